// Round 10
// baseline (241.709 us; speedup 1.0000x reference)
//
#include <hip/hip_runtime.h>
#include <hip/hip_cooperative_groups.h>

namespace cg = cooperative_groups;

typedef __bf16 bf16_t;
typedef __bf16 bf16x4 __attribute__((ext_vector_type(4)));
typedef __bf16 bf16x8 __attribute__((ext_vector_type(8)));
typedef float f32x4 __attribute__((ext_vector_type(4)));

#define T_SEQ 1024
#define EMB   512
#define NH    8
#define HD    64
#define BATCH 2
#define NBH   (BATCH*NH)      // 16
#define CHUNK 64
#define NCHUNK (T_SEQ/CHUNK)  // 16
#define NBLK  (NBH*NCHUNK)    // 256
#define LDA   72              // padded LDS row stride
#define N_X   (BATCH*T_SEQ*EMB)   // 1048576
#define N_WQ  (3*EMB*EMB)         //  786432
#define N_WO  (EMB*EMB)           //  262144
#define NTD   (NBH*T_SEQ*HD)      // 1048576

// Identity: with ang_t = (pi/2)*t/T,
//   q_cos[t].k_cos[s] + q_sin[t].k_sin[s] = (q'[t].k'[s]) * cos(ang_t - ang_s)

// ===========================================================================
// FUSED cooperative kernel: 256 blocks x 256 threads, grid.sync between
// stages. Stage bodies are the R9-proven code verbatim (block index remapped).
// ===========================================================================
__global__ __launch_bounds__(256) void fused_kernel(
    const float* __restrict__ x, const float* __restrict__ wq32,
    const float* __restrict__ bq, const float* __restrict__ wo32,
    const float* __restrict__ bo, float* __restrict__ out,
    char* __restrict__ ws)
{
    // workspace layout (identical to fallback host layout)
    bf16_t* xb  = (bf16_t*)ws;
    bf16_t* wqb = xb + N_X;
    bf16_t* wob = wqb + N_WQ;
    bf16_t* qq  = wob + N_WO;
    bf16_t* kk  = qq + NTD;
    bf16_t* vv  = kk + NTD;
    bf16_t* Y   = vv + NTD;
    bf16_t* SscT = Y + NTD;
    bf16_t* SssT = SscT + (size_t)NBLK * HD * HD;
    float* zc = (float*)(SssT + (size_t)NBLK * HD * HD);
    float* zs = zc + (size_t)NBLK * HD;

    // shared memory, reused across stages
    __shared__ __align__(16) bf16_t s_a[CHUNK * LDA];
    __shared__ __align__(16) bf16_t s_b[CHUNK * LDA];
    __shared__ __align__(16) bf16_t s_c[CHUNK * LDA];
    __shared__ __align__(16) bf16_t s_d[CHUNK * LDA];
    __shared__ __align__(16) bf16_t s_e[CHUNK * LDA];
    __shared__ __align__(16) bf16_t s_f[CHUNK * LDA];
    __shared__ float f_a[CHUNK], f_b[CHUNK], f_c[CHUNK];
    __shared__ float f_d[CHUNK], f_e[CHUNK], f_f[CHUNK];

    cg::grid_group grid = cg::this_grid();
    const int blk = blockIdx.x;

    // ---- S0: fp32 -> bf16 convert (x | w_qkv | w_out) ----
    {
        const int tid = blk * 256 + threadIdx.x;
        for (int i = tid; i < 524288; i += 65536) {
            const float* s; bf16_t* d; int off;
            if (i < 262144)      { s = x;    d = xb;  off = i; }
            else if (i < 458752) { s = wq32; d = wqb; off = i - 262144; }
            else                 { s = wo32; d = wob; off = i - 458752; }
            float4 v = ((const float4*)s)[off];
            bf16x4 o;
            o[0] = (bf16_t)v.x; o[1] = (bf16_t)v.y;
            o[2] = (bf16_t)v.z; o[3] = (bf16_t)v.w;
            ((bf16x4*)d)[off] = o;
        }
    }
    grid.sync();

    // ---- S1: qkv GEMM, 768 64x64 one-wave tiles, 3 waves/block ----
    {
        const int w = threadIdx.x >> 6;
        const int lane = threadIdx.x & 63;
        if (w < 3) {
            const int gt = blk * 3 + w;            // 0..767
            const int m0 = (gt & 31) * 64;
            const int n0 = (gt >> 5) * 64;
            const int rsel = lane & 15;
            const int koff = (lane >> 4) * 8;
            f32x4 acc[4][4] = {};
            const bf16_t* Ap = xb + (m0 + rsel) * EMB + koff;
            const bf16_t* Bp = wqb + (n0 + rsel) * EMB + koff;
#pragma unroll 2
            for (int k0 = 0; k0 < EMB; k0 += 32) {
                bf16x8 af[4], bfr[4];
                for (int i = 0; i < 4; ++i)
                    af[i] = *(const bf16x8*)(Ap + i * 16 * EMB + k0);
                for (int j = 0; j < 4; ++j)
                    bfr[j] = *(const bf16x8*)(Bp + j * 16 * EMB + k0);
                for (int i = 0; i < 4; ++i)
                    for (int j = 0; j < 4; ++j)
                        acc[i][j] = __builtin_amdgcn_mfma_f32_16x16x32_bf16(
                            af[i], bfr[j], acc[i][j], 0, 0, 0);
            }
            for (int j = 0; j < 4; ++j) {
                const int n = n0 + j * 16 + rsel;
                const float bn = bq[n];
                const int sec = n >> 9;          // 0=q 1=k 2=v
                const int c = n & 511;
                const int h = c >> 6, e = c & 63;
                for (int i = 0; i < 4; ++i) {
                    const int mb = m0 + i * 16 + (lane >> 4) * 4;
                    for (int r = 0; r < 4; ++r) {
                        int m = mb + r;
                        int b = m >> 10, t = m & 1023;
                        float val = acc[i][j][r] + bn;
                        int di = ((b * NH + h) * T_SEQ + t) * HD + e;
                        if (sec == 0) {
                            qq[di] = (bf16_t)fmaxf(val, 0.f);
                        } else if (sec == 1) {
                            kk[di] = (bf16_t)fmaxf(val, 0.f);
                        } else {
                            vv[di] = (bf16_t)val;
                        }
                    }
                }
            }
        }
    }
    grid.sync();

    // ---- S2: chunk_sum (blk = chunk block), S transposed [e][i] ----
    {
        const int ch = blk & 15;
        bf16_t* sk = s_a;                 // CHUNK*HD used (<= CHUNK*LDA)
        bf16_t* sv = s_b;
        float* cwt = f_a; float* swt = f_b;
        const int base = blk * CHUNK * HD;
        for (int i = threadIdx.x; i < CHUNK * HD / 8; i += 256) {
            ((uint4*)sk)[i] = ((const uint4*)(kk + base))[i];
            ((uint4*)sv)[i] = ((const uint4*)(vv + base))[i];
        }
        if (threadIdx.x < CHUNK) {
            int tg = ch * CHUNK + threadIdx.x;
            float ang = 1.5707963267948966f * (float)tg * (1.0f / (float)T_SEQ);
            cwt[threadIdx.x] = cosf(ang);
            swt[threadIdx.x] = sinf(ang);
        }
        __syncthreads();
        const int i  = threadIdx.x & 63;
        const int jg = (threadIdx.x >> 6) * 16;
        float ac[16], as[16];
        for (int jj = 0; jj < 16; ++jj) { ac[jj] = 0.f; as[jj] = 0.f; }
        for (int t = 0; t < CHUNK; ++t) {
            float kv = (float)sk[t * HD + i];
            float kc_ = kv * cwt[t];
            float ks_ = kv * swt[t];
            for (int jj = 0; jj < 16; ++jj) {
                float vj = (float)sv[t * HD + jg + jj];
                ac[jj] += kc_ * vj;
                as[jj] += ks_ * vj;
            }
        }
        bf16_t* oc = SscT + blk * HD * HD;
        bf16_t* os = SssT + blk * HD * HD;
        for (int jj = 0; jj < 16; ++jj) {
            oc[(jg + jj) * HD + i] = (bf16_t)ac[jj];   // transposed: [e][i]
            os[(jg + jj) * HD + i] = (bf16_t)as[jj];
        }
        if (threadIdx.x < HD) {
            int ii = threadIdx.x;
            float s = 0.f;
            for (int t = 0; t < CHUNK; ++t) s += (float)sk[t * HD + ii] * cwt[t];
            zc[blk * HD + ii] = s;
        } else if (threadIdx.x < 2 * HD) {
            int ii = threadIdx.x - HD;
            float s = 0.f;
            for (int t = 0; t < CHUNK; ++t) s += (float)sk[t * HD + ii] * swt[t];
            zs[blk * HD + ii] = s;
        }
    }
    grid.sync();

    // ---- S3: chunk_out (blk = chunk block) ----
    {
        const int bh = blk >> 4, ch = blk & 15;
        bf16_t* sq = s_a;  bf16_t* sk = s_b;  bf16_t* svT = s_c;
        bf16_t* sct = s_d; bf16_t* sst = s_e; bf16_t* sp  = s_f;
        float* cwt = f_a; float* swt = f_b; float* cosd = f_c;
        float* zcl = f_d; float* zsl = f_e; float* nrm = f_f;

        const int base = blk * CHUNK * HD;
        for (int i = threadIdx.x; i < CHUNK * HD / 8; i += 256) {
            int row = i >> 3, g = i & 7;
            ((uint4*)(sq + row * LDA))[g]  = ((const uint4*)(qq + base))[i];
            ((uint4*)(sk + row * LDA))[g]  = ((const uint4*)(kk + base))[i];
            bf16x8 v8 = *(const bf16x8*)(vv + base + i * 8);
            int t = i >> 3, e0 = (i & 7) * 8;
            for (int j = 0; j < 8; ++j) svT[(e0 + j) * LDA + t] = v8[j];
        }
        // on-the-fly exclusive prefix of S over chunks < ch
        {
            const int e0 = threadIdx.x * 16;
            float accC[16], accS[16];
            for (int j = 0; j < 16; ++j) { accC[j] = 0.f; accS[j] = 0.f; }
            const int sb = bh * NCHUNK * HD * HD + e0;
            for (int c = 0; c < ch; ++c) {
                const bf16x8* pc = (const bf16x8*)(SscT + sb + c * HD * HD);
                const bf16x8* ps = (const bf16x8*)(SssT + sb + c * HD * HD);
                bf16x8 c0 = pc[0], c1 = pc[1], s0 = ps[0], s1 = ps[1];
                for (int j = 0; j < 8; ++j) {
                    accC[j] += (float)c0[j];  accC[8 + j] += (float)c1[j];
                    accS[j] += (float)s0[j];  accS[8 + j] += (float)s1[j];
                }
            }
            const int row = threadIdx.x >> 2, col = (threadIdx.x & 3) * 16;
            bf16x8 oc0, oc1, os0, os1;
            for (int j = 0; j < 8; ++j) {
                oc0[j] = (bf16_t)accC[j];  oc1[j] = (bf16_t)accC[8 + j];
                os0[j] = (bf16_t)accS[j];  os1[j] = (bf16_t)accS[8 + j];
            }
            *(bf16x8*)(sct + row * LDA + col) = oc0;
            *(bf16x8*)(sct + row * LDA + col + 8) = oc1;
            *(bf16x8*)(sst + row * LDA + col) = os0;
            *(bf16x8*)(sst + row * LDA + col + 8) = os1;
        }
        if (threadIdx.x < HD) {
            int tl = threadIdx.x;
            float s = 0.f;
            for (int c = 0; c < ch; ++c) s += zc[(bh * NCHUNK + c) * HD + tl];
            zcl[tl] = s;
            int tg = ch * CHUNK + tl;
            float angg = 1.5707963267948966f * (float)tg * (1.0f / (float)T_SEQ);
            cwt[tl] = cosf(angg);
            swt[tl] = sinf(angg);
            cosd[tl] = cosf(1.5707963267948966f * (float)tl * (1.0f / (float)T_SEQ));
        } else if (threadIdx.x < 2 * HD) {
            int i = threadIdx.x - HD;
            float s = 0.f;
            for (int c = 0; c < ch; ++c) s += zs[(bh * NCHUNK + c) * HD + i];
            zsl[i] = s;
        }
        __syncthreads();

        const int w = threadIdx.x >> 6;
        const int lane = threadIdx.x & 63;
        const int rsel = lane & 15;
        const int koff = (lane >> 4) * 8;
        const int myrow = w * 16 + rsel;

        bf16x8 aq0 = *(const bf16x8*)(sq + myrow * LDA + koff);
        bf16x8 aq1 = *(const bf16x8*)(sq + myrow * LDA + koff + 32);
        for (int nt = 0; nt < 4; ++nt) {
            const int n0 = nt * 16;
            f32x4 pacc = {0.f, 0.f, 0.f, 0.f};
            bf16x8 b0 = *(const bf16x8*)(sk + (n0 + rsel) * LDA + koff);
            bf16x8 b1 = *(const bf16x8*)(sk + (n0 + rsel) * LDA + koff + 32);
            pacc = __builtin_amdgcn_mfma_f32_16x16x32_bf16(aq0, b0, pacc, 0, 0, 0);
            pacc = __builtin_amdgcn_mfma_f32_16x16x32_bf16(aq1, b1, pacc, 0, 0, 0);
            const int s = n0 + (lane & 15);
            const int tb = w * 16 + (lane >> 4) * 4;
            for (int r = 0; r < 4; ++r) {
                int t = tb + r;
                float p = (s <= t) ? pacc[r] * cosd[t - s] : 0.f;
                sp[t * LDA + s] = (bf16_t)p;
            }
        }

        if (lane < 16) {
            int row = w * 16 + lane;
            float nv = 0.f;
            const bf16x8* pr = (const bf16x8*)(sp + row * LDA);
            for (int g = 0; g < 8; ++g) {
                bf16x8 pv = pr[g];
                for (int j = 0; j < 8; ++j) nv += (float)pv[j];
            }
            float cwr = cwt[row], swr = swt[row];
            const bf16x8* qr = (const bf16x8*)(sq + row * LDA);
            for (int g = 0; g < 8; ++g) {
                bf16x8 qv = qr[g];
                for (int j = 0; j < 8; ++j)
                    nv += (float)qv[j] * (cwr * zcl[g * 8 + j] + swr * zsl[g * 8 + j]);
            }
            nrm[row] = nv;
        }

        const float cwq = cwt[myrow], swq = swt[myrow];
        bf16x8 qc0, qc1, qs0, qs1;
        for (int j = 0; j < 8; ++j) {
            qc0[j] = (bf16_t)((float)aq0[j] * cwq);
            qc1[j] = (bf16_t)((float)aq1[j] * cwq);
            qs0[j] = (bf16_t)((float)aq0[j] * swq);
            qs1[j] = (bf16_t)((float)aq1[j] * swq);
        }
        bf16x8 ap0 = *(const bf16x8*)(sp + myrow * LDA + koff);
        bf16x8 ap1 = *(const bf16x8*)(sp + myrow * LDA + koff + 32);

        // nrm[] written by lanes<16 of this wave; rows are wave-local, and
        // LDS writes are visible within the wave without a barrier, but the
        // compiler needs s_waitcnt — __syncthreads preserved from R9 semantics
        __syncthreads();

        const int b = bh >> 3, h = bh & 7;
        for (int nt = 0; nt < 4; ++nt) {
            const int n0 = nt * 16;
            const bf16_t* bvp = svT + (n0 + rsel) * LDA + koff;
            const bf16_t* bcp = sct + (n0 + rsel) * LDA + koff;
            const bf16_t* bsp = sst + (n0 + rsel) * LDA + koff;
            f32x4 acc = {0.f, 0.f, 0.f, 0.f};
            acc = __builtin_amdgcn_mfma_f32_16x16x32_bf16(ap0, *(const bf16x8*)(bvp), acc, 0, 0, 0);
            acc = __builtin_amdgcn_mfma_f32_16x16x32_bf16(ap1, *(const bf16x8*)(bvp + 32), acc, 0, 0, 0);
            acc = __builtin_amdgcn_mfma_f32_16x16x32_bf16(qc0, *(const bf16x8*)(bcp), acc, 0, 0, 0);
            acc = __builtin_amdgcn_mfma_f32_16x16x32_bf16(qc1, *(const bf16x8*)(bcp + 32), acc, 0, 0, 0);
            acc = __builtin_amdgcn_mfma_f32_16x16x32_bf16(qs0, *(const bf16x8*)(bsp), acc, 0, 0, 0);
            acc = __builtin_amdgcn_mfma_f32_16x16x32_bf16(qs1, *(const bf16x8*)(bsp + 32), acc, 0, 0, 0);
            const int col = n0 + (lane & 15);
            const int tb = w * 16 + (lane >> 4) * 4;
            for (int r = 0; r < 4; ++r) {
                int row = tb + r;
                float inv = 1.0f / (nrm[row] + 1e-6f);
                int tg = ch * CHUNK + row;
                Y[((b * T_SEQ + tg) * EMB) + h * HD + col] = (bf16_t)(acc[r] * inv);
            }
        }
    }
    grid.sync();

    // ---- S4: out GEMM, 256 blocks = 32 x 8 tiles of 64x64 ----
    {
        const int w = threadIdx.x >> 6;
        const int lane = threadIdx.x & 63;
        const int rsel = lane & 15;
        const int koff = (lane >> 4) * 8;
        const int m0 = (blk & 31) * 64 + (w & 1) * 32;
        const int n0 = (blk >> 5) * 64 + (w >> 1) * 32;
        f32x4 acc[2][2] = {};
        const bf16_t* Ap = Y + (m0 + rsel) * EMB + koff;
        const bf16_t* Bp = wob + (n0 + rsel) * EMB + koff;
#pragma unroll 4
        for (int k0 = 0; k0 < EMB; k0 += 32) {
            bf16x8 af[2], bfr[2];
            for (int i = 0; i < 2; ++i)
                af[i] = *(const bf16x8*)(Ap + i * 16 * EMB + k0);
            for (int j = 0; j < 2; ++j)
                bfr[j] = *(const bf16x8*)(Bp + j * 16 * EMB + k0);
            for (int i = 0; i < 2; ++i)
                for (int j = 0; j < 2; ++j)
                    acc[i][j] = __builtin_amdgcn_mfma_f32_16x16x32_bf16(
                        af[i], bfr[j], acc[i][j], 0, 0, 0);
        }
        for (int j = 0; j < 2; ++j) {
            const int n = n0 + j * 16 + rsel;
            const float bn = bo[n];
            for (int i = 0; i < 2; ++i) {
                const int mb = m0 + i * 16 + (lane >> 4) * 4;
                for (int r = 0; r < 4; ++r)
                    out[(mb + r) * EMB + n] = acc[i][j][r] + bn;
            }
        }
    }
}

// ===========================================================================
// Fallback path: R9-proven 5-dispatch pipeline (used if cooperative launch
// is rejected, e.g. under graph capture on older ROCm).
// ===========================================================================
__global__ __launch_bounds__(256) void cvt3_kernel(
    const float* __restrict__ x, const float* __restrict__ wq,
    const float* __restrict__ wo,
    bf16_t* __restrict__ xb, bf16_t* __restrict__ wqb, bf16_t* __restrict__ wob)
{
    int i = blockIdx.x * 256 + threadIdx.x;
    const float* s; bf16_t* d; int off;
    if (i < 262144)      { s = x;  d = xb;  off = i; }
    else if (i < 458752) { s = wq; d = wqb; off = i - 262144; }
    else                 { s = wo; d = wob; off = i - 458752; }
    float4 v = ((const float4*)s)[off];
    bf16x4 o;
    o[0] = (bf16_t)v.x; o[1] = (bf16_t)v.y;
    o[2] = (bf16_t)v.z; o[3] = (bf16_t)v.w;
    ((bf16x4*)d)[off] = o;
}

__global__ __launch_bounds__(64) void qkv_gemm_kernel(
    const bf16_t* __restrict__ X, const bf16_t* __restrict__ W,
    const float* __restrict__ bias,
    bf16_t* __restrict__ qq, bf16_t* __restrict__ kk, bf16_t* __restrict__ vv)
{
    const int lane = threadIdx.x;
    const int rsel = lane & 15;
    const int koff = (lane >> 4) * 8;
    const int m0 = blockIdx.x * 64;
    const int n0 = blockIdx.y * 64;
    f32x4 acc[4][4] = {};
    const bf16_t* Ap = X + (m0 + rsel) * EMB + koff;
    const bf16_t* Bp = W + (n0 + rsel) * EMB + koff;
#pragma unroll 2
    for (int k0 = 0; k0 < EMB; k0 += 32) {
        bf16x8 af[4], bfr[4];
        for (int i = 0; i < 4; ++i)
            af[i] = *(const bf16x8*)(Ap + i * 16 * EMB + k0);
        for (int j = 0; j < 4; ++j)
            bfr[j] = *(const bf16x8*)(Bp + j * 16 * EMB + k0);
        for (int i = 0; i < 4; ++i)
            for (int j = 0; j < 4; ++j)
                acc[i][j] = __builtin_amdgcn_mfma_f32_16x16x32_bf16(
                    af[i], bfr[j], acc[i][j], 0, 0, 0);
    }
    for (int j = 0; j < 4; ++j) {
        const int n = n0 + j * 16 + rsel;
        const float bn = bias[n];
        const int sec = n >> 9;
        const int c = n & 511;
        const int h = c >> 6, e = c & 63;
        for (int i = 0; i < 4; ++i) {
            const int mb = m0 + i * 16 + (lane >> 4) * 4;
            for (int r = 0; r < 4; ++r) {
                int m = mb + r;
                int b = m >> 10, t = m & 1023;
                float val = acc[i][j][r] + bn;
                int di = ((b * NH + h) * T_SEQ + t) * HD + e;
                if (sec == 0) {
                    qq[di] = (bf16_t)fmaxf(val, 0.f);
                } else if (sec == 1) {
                    kk[di] = (bf16_t)fmaxf(val, 0.f);
                } else {
                    vv[di] = (bf16_t)val;
                }
            }
        }
    }
}

__global__ __launch_bounds__(256) void chunk_sum_kernel(
    const bf16_t* __restrict__ kk, const bf16_t* __restrict__ vv,
    bf16_t* __restrict__ Ssc, bf16_t* __restrict__ Sss,
    float* __restrict__ zc, float* __restrict__ zs)
{
    const int blk = blockIdx.x;
    const int ch = blk & 15;
    __shared__ __align__(16) bf16_t sk[CHUNK * HD];
    __shared__ __align__(16) bf16_t sv[CHUNK * HD];
    __shared__ float cwt[CHUNK], swt[CHUNK];
    const int base = blk * CHUNK * HD;
    for (int i = threadIdx.x; i < CHUNK * HD / 8; i += 256) {
        ((uint4*)sk)[i] = ((const uint4*)(kk + base))[i];
        ((uint4*)sv)[i] = ((const uint4*)(vv + base))[i];
    }
    if (threadIdx.x < CHUNK) {
        int tg = ch * CHUNK + threadIdx.x;
        float ang = 1.5707963267948966f * (float)tg * (1.0f / (float)T_SEQ);
        cwt[threadIdx.x] = cosf(ang);
        swt[threadIdx.x] = sinf(ang);
    }
    __syncthreads();
    const int i  = threadIdx.x & 63;
    const int jg = (threadIdx.x >> 6) * 16;
    float ac[16], as[16];
    for (int jj = 0; jj < 16; ++jj) { ac[jj] = 0.f; as[jj] = 0.f; }
    for (int t = 0; t < CHUNK; ++t) {
        float kv = (float)sk[t * HD + i];
        float kc_ = kv * cwt[t];
        float ks_ = kv * swt[t];
        for (int jj = 0; jj < 16; ++jj) {
            float vj = (float)sv[t * HD + jg + jj];
            ac[jj] += kc_ * vj;
            as[jj] += ks_ * vj;
        }
    }
    bf16_t* oc = Ssc + blk * HD * HD;
    bf16_t* os = Sss + blk * HD * HD;
    for (int jj = 0; jj < 16; ++jj) {
        oc[(jg + jj) * HD + i] = (bf16_t)ac[jj];
        os[(jg + jj) * HD + i] = (bf16_t)as[jj];
    }
    if (threadIdx.x < HD) {
        int ii = threadIdx.x;
        float s = 0.f;
        for (int t = 0; t < CHUNK; ++t) s += (float)sk[t * HD + ii] * cwt[t];
        zc[blk * HD + ii] = s;
    } else if (threadIdx.x < 2 * HD) {
        int ii = threadIdx.x - HD;
        float s = 0.f;
        for (int t = 0; t < CHUNK; ++t) s += (float)sk[t * HD + ii] * swt[t];
        zs[blk * HD + ii] = s;
    }
}

__global__ __launch_bounds__(256) void chunk_out_kernel(
    const bf16_t* __restrict__ qq, const bf16_t* __restrict__ kk,
    const bf16_t* __restrict__ vv,
    const bf16_t* __restrict__ SscT, const bf16_t* __restrict__ SssT,
    const float* __restrict__ zc, const float* __restrict__ zs,
    bf16_t* __restrict__ Y)
{
    const int blk = blockIdx.x;
    const int bh = blk >> 4, ch = blk & 15;
    __shared__ __align__(16) bf16_t sq [CHUNK * LDA];
    __shared__ __align__(16) bf16_t sk [CHUNK * LDA];
    __shared__ __align__(16) bf16_t svT[CHUNK * LDA];
    __shared__ __align__(16) bf16_t sct[CHUNK * LDA];
    __shared__ __align__(16) bf16_t sst[CHUNK * LDA];
    __shared__ __align__(16) bf16_t sp [CHUNK * LDA];
    __shared__ float cwt[CHUNK], swt[CHUNK], cosd[CHUNK];
    __shared__ float zcl[CHUNK], zsl[CHUNK], nrm[CHUNK];

    const int base = blk * CHUNK * HD;
    for (int i = threadIdx.x; i < CHUNK * HD / 8; i += 256) {
        int row = i >> 3, g = i & 7;
        ((uint4*)(sq + row * LDA))[g]  = ((const uint4*)(qq + base))[i];
        ((uint4*)(sk + row * LDA))[g]  = ((const uint4*)(kk + base))[i];
        bf16x8 v8 = *(const bf16x8*)(vv + base + i * 8);
        int t = i >> 3, e0 = (i & 7) * 8;
        for (int j = 0; j < 8; ++j) svT[(e0 + j) * LDA + t] = v8[j];
    }
    {
        const int e0 = threadIdx.x * 16;
        float accC[16], accS[16];
        for (int j = 0; j < 16; ++j) { accC[j] = 0.f; accS[j] = 0.f; }
        const int sb = bh * NCHUNK * HD * HD + e0;
        for (int c = 0; c < ch; ++c) {
            const bf16x8* pc = (const bf16x8*)(SscT + sb + c * HD * HD);
            const bf16x8* ps = (const bf16x8*)(SssT + sb + c * HD * HD);
            bf16x8 c0 = pc[0], c1 = pc[1], s0 = ps[0], s1 = ps[1];
            for (int j = 0; j < 8; ++j) {
                accC[j] += (float)c0[j];  accC[8 + j] += (float)c1[j];
                accS[j] += (float)s0[j];  accS[8 + j] += (float)s1[j];
            }
        }
        const int row = threadIdx.x >> 2, col = (threadIdx.x & 3) * 16;
        bf16x8 oc0, oc1, os0, os1;
        for (int j = 0; j < 8; ++j) {
            oc0[j] = (bf16_t)accC[j];  oc1[j] = (bf16_t)accC[8 + j];
            os0[j] = (bf16_t)accS[j];  os1[j] = (bf16_t)accS[8 + j];
        }
        *(bf16x8*)(sct + row * LDA + col) = oc0;
        *(bf16x8*)(sct + row * LDA + col + 8) = oc1;
        *(bf16x8*)(sst + row * LDA + col) = os0;
        *(bf16x8*)(sst + row * LDA + col + 8) = os1;
    }
    if (threadIdx.x < HD) {
        int tl = threadIdx.x;
        float s = 0.f;
        for (int c = 0; c < ch; ++c) s += zc[(bh * NCHUNK + c) * HD + tl];
        zcl[tl] = s;
        int tg = ch * CHUNK + tl;
        float angg = 1.5707963267948966f * (float)tg * (1.0f / (float)T_SEQ);
        cwt[tl] = cosf(angg);
        swt[tl] = sinf(angg);
        cosd[tl] = cosf(1.5707963267948966f * (float)tl * (1.0f / (float)T_SEQ));
    } else if (threadIdx.x < 2 * HD) {
        int i = threadIdx.x - HD;
        float s = 0.f;
        for (int c = 0; c < ch; ++c) s += zs[(bh * NCHUNK + c) * HD + i];
        zsl[i] = s;
    }
    __syncthreads();

    const int w = threadIdx.x >> 6;
    const int lane = threadIdx.x & 63;
    const int rsel = lane & 15;
    const int koff = (lane >> 4) * 8;
    const int myrow = w * 16 + rsel;

    bf16x8 aq0 = *(const bf16x8*)(sq + myrow * LDA + koff);
    bf16x8 aq1 = *(const bf16x8*)(sq + myrow * LDA + koff + 32);
    for (int nt = 0; nt < 4; ++nt) {
        const int n0 = nt * 16;
        f32x4 pacc = {0.f, 0.f, 0.f, 0.f};
        bf16x8 b0 = *(const bf16x8*)(sk + (n0 + rsel) * LDA + koff);
        bf16x8 b1 = *(const bf16x8*)(sk + (n0 + rsel) * LDA + koff + 32);
        pacc = __builtin_amdgcn_mfma_f32_16x16x32_bf16(aq0, b0, pacc, 0, 0, 0);
        pacc = __builtin_amdgcn_mfma_f32_16x16x32_bf16(aq1, b1, pacc, 0, 0, 0);
        const int s = n0 + (lane & 15);
        const int tb = w * 16 + (lane >> 4) * 4;
        for (int r = 0; r < 4; ++r) {
            int t = tb + r;
            float p = (s <= t) ? pacc[r] * cosd[t - s] : 0.f;
            sp[t * LDA + s] = (bf16_t)p;
        }
    }

    if (lane < 16) {
        int row = w * 16 + lane;
        float nv = 0.f;
        const bf16x8* pr = (const bf16x8*)(sp + row * LDA);
        for (int g = 0; g < 8; ++g) {
            bf16x8 pv = pr[g];
            for (int j = 0; j < 8; ++j) nv += (float)pv[j];
        }
        float cwr = cwt[row], swr = swt[row];
        const bf16x8* qr = (const bf16x8*)(sq + row * LDA);
        for (int g = 0; g < 8; ++g) {
            bf16x8 qv = qr[g];
            for (int j = 0; j < 8; ++j)
                nv += (float)qv[j] * (cwr * zcl[g * 8 + j] + swr * zsl[g * 8 + j]);
        }
        nrm[row] = nv;
    }

    const float cwq = cwt[myrow], swq = swt[myrow];
    bf16x8 qc0, qc1, qs0, qs1;
    for (int j = 0; j < 8; ++j) {
        qc0[j] = (bf16_t)((float)aq0[j] * cwq);
        qc1[j] = (bf16_t)((float)aq1[j] * cwq);
        qs0[j] = (bf16_t)((float)aq0[j] * swq);
        qs1[j] = (bf16_t)((float)aq1[j] * swq);
    }
    bf16x8 ap0 = *(const bf16x8*)(sp + myrow * LDA + koff);
    bf16x8 ap1 = *(const bf16x8*)(sp + myrow * LDA + koff + 32);

    const int b = bh >> 3, h = bh & 7;
    for (int nt = 0; nt < 4; ++nt) {
        const int n0 = nt * 16;
        const bf16_t* bvp = svT + (n0 + rsel) * LDA + koff;
        const bf16_t* bcp = sct + (n0 + rsel) * LDA + koff;
        const bf16_t* bsp = sst + (n0 + rsel) * LDA + koff;
        f32x4 acc = {0.f, 0.f, 0.f, 0.f};
        acc = __builtin_amdgcn_mfma_f32_16x16x32_bf16(ap0, *(const bf16x8*)(bvp), acc, 0, 0, 0);
        acc = __builtin_amdgcn_mfma_f32_16x16x32_bf16(ap1, *(const bf16x8*)(bvp + 32), acc, 0, 0, 0);
        acc = __builtin_amdgcn_mfma_f32_16x16x32_bf16(qc0, *(const bf16x8*)(bcp), acc, 0, 0, 0);
        acc = __builtin_amdgcn_mfma_f32_16x16x32_bf16(qc1, *(const bf16x8*)(bcp + 32), acc, 0, 0, 0);
        acc = __builtin_amdgcn_mfma_f32_16x16x32_bf16(qs0, *(const bf16x8*)(bsp), acc, 0, 0, 0);
        acc = __builtin_amdgcn_mfma_f32_16x16x32_bf16(qs1, *(const bf16x8*)(bsp + 32), acc, 0, 0, 0);
        const int col = n0 + (lane & 15);
        const int tb = w * 16 + (lane >> 4) * 4;
        for (int r = 0; r < 4; ++r) {
            int row = tb + r;
            float inv = 1.0f / (nrm[row] + 1e-6f);
            int tg = ch * CHUNK + row;
            Y[((b * T_SEQ + tg) * EMB) + h * HD + col] = (bf16_t)(acc[r] * inv);
        }
    }
}

__global__ __launch_bounds__(256) void out_gemm_kernel(
    const bf16_t* __restrict__ Yb, const bf16_t* __restrict__ W,
    const float* __restrict__ bias, float* __restrict__ out)
{
    const int w = threadIdx.x >> 6;
    const int lane = threadIdx.x & 63;
    const int rsel = lane & 15;
    const int koff = (lane >> 4) * 8;
    const int m0 = blockIdx.x * 64 + (w & 1) * 32;
    const int n0 = blockIdx.y * 64 + (w >> 1) * 32;
    f32x4 acc[2][2] = {};
    const bf16_t* Ap = Yb + (m0 + rsel) * EMB + koff;
    const bf16_t* Bp = W + (n0 + rsel) * EMB + koff;
#pragma unroll 4
    for (int k0 = 0; k0 < EMB; k0 += 32) {
        bf16x8 af[2], bfr[2];
        for (int i = 0; i < 2; ++i)
            af[i] = *(const bf16x8*)(Ap + i * 16 * EMB + k0);
        for (int j = 0; j < 2; ++j)
            bfr[j] = *(const bf16x8*)(Bp + j * 16 * EMB + k0);
        for (int i = 0; i < 2; ++i)
            for (int j = 0; j < 2; ++j)
                acc[i][j] = __builtin_amdgcn_mfma_f32_16x16x32_bf16(
                    af[i], bfr[j], acc[i][j], 0, 0, 0);
    }
    for (int j = 0; j < 2; ++j) {
        const int n = n0 + j * 16 + rsel;
        const float bn = bias[n];
        for (int i = 0; i < 2; ++i) {
            const int mb = m0 + i * 16 + (lane >> 4) * 4;
            for (int r = 0; r < 4; ++r)
                out[(mb + r) * EMB + n] = acc[i][j][r] + bn;
        }
    }
}

extern "C" void kernel_launch(void* const* d_in, const int* in_sizes, int n_in,
                              void* d_out, int out_size, void* d_ws, size_t ws_size,
                              hipStream_t stream) {
    const float* x     = (const float*)d_in[0];
    const float* w_qkv = (const float*)d_in[1];
    const float* b_qkv = (const float*)d_in[2];
    const float* w_out = (const float*)d_in[3];
    const float* b_out = (const float*)d_in[4];
    float* out = (float*)d_out;
    char* wsb = (char*)d_ws;

    // Try the single fused cooperative dispatch first.
    void* params[7] = {
        (void*)&x, (void*)&w_qkv, (void*)&b_qkv, (void*)&w_out,
        (void*)&b_out, (void*)&out, (void*)&wsb
    };
    hipError_t err = hipLaunchCooperativeKernel(
        (const void*)fused_kernel, dim3(256), dim3(256), params, 0, stream);
    if (err == hipSuccess) return;
    (void)hipGetLastError();   // clear sticky error; fall back below

    // Fallback: R9-proven 5-dispatch pipeline (identical math).
    char* w = wsb;
    bf16_t* xb   = (bf16_t*)w;                 w += (size_t)N_X  * sizeof(bf16_t);
    bf16_t* wqb  = (bf16_t*)w;                 w += (size_t)N_WQ * sizeof(bf16_t);
    bf16_t* wob  = (bf16_t*)w;                 w += (size_t)N_WO * sizeof(bf16_t);
    const size_t SZ_BHTD = (size_t)NTD * sizeof(bf16_t);
    bf16_t* qq = (bf16_t*)w;                   w += SZ_BHTD;
    bf16_t* kk = (bf16_t*)w;                   w += SZ_BHTD;
    bf16_t* vv = (bf16_t*)w;                   w += SZ_BHTD;
    bf16_t* Y  = (bf16_t*)w;                   w += SZ_BHTD;
    bf16_t* SscT = (bf16_t*)w;                 w += (size_t)NBLK * HD * HD * sizeof(bf16_t);
    bf16_t* SssT = (bf16_t*)w;                 w += (size_t)NBLK * HD * HD * sizeof(bf16_t);
    float* zc = (float*)w;                     w += (size_t)NBLK * HD * sizeof(float);
    float* zs = (float*)w;

    cvt3_kernel<<<2048, 256, 0, stream>>>(x, w_qkv, w_out, xb, wqb, wob);
    qkv_gemm_kernel<<<dim3(2048 / 64, 1536 / 64), 64, 0, stream>>>(
        xb, wqb, b_qkv, qq, kk, vv);
    chunk_sum_kernel<<<NBLK, 256, 0, stream>>>(kk, vv, SscT, SssT, zc, zs);
    chunk_out_kernel<<<NBLK, 256, 0, stream>>>(qq, kk, vv, SscT, SssT, zc, zs, Y);
    out_gemm_kernel<<<dim3(2048 / 64, 512 / 64), 256, 0, stream>>>(
        Y, wob, b_out, out);
}

// Round 11
// 139.921 us; speedup vs baseline: 1.7275x; 1.7275x over previous
//
#include <hip/hip_runtime.h>

typedef __bf16 bf16_t;
typedef __bf16 bf16x4 __attribute__((ext_vector_type(4)));
typedef __bf16 bf16x8 __attribute__((ext_vector_type(8)));
typedef float f32x4 __attribute__((ext_vector_type(4)));

#define T_SEQ 1024
#define EMB   512
#define NH    8
#define HD    64
#define BATCH 2
#define NBH   (BATCH*NH)      // 16
#define CHUNK 64
#define NCHUNK (T_SEQ/CHUNK)  // 16
#define NBLK  (NBH*NCHUNK)    // 256
#define LDA   72              // padded LDS row stride

// Identity: with ang_t = (pi/2)*t/T,
//   q_cos[t].k_cos[s] + q_sin[t].k_sin[s] = (q'[t].k'[s]) * cos(ang_t - ang_s)

// ---------------------------------------------------------------------------
// K0: fused fp32 -> bf16 convert for x, w_qkv, w_out (one dispatch).
// ---------------------------------------------------------------------------
__global__ __launch_bounds__(256) void cvt3_kernel(
    const float* __restrict__ x, const float* __restrict__ wq,
    const float* __restrict__ wo,
    bf16_t* __restrict__ xb, bf16_t* __restrict__ wqb, bf16_t* __restrict__ wob)
{
    int i = blockIdx.x * 256 + threadIdx.x;
    const float* s; bf16_t* d; int off;
    if (i < 262144)      { s = x;  d = xb;  off = i; }
    else if (i < 458752) { s = wq; d = wqb; off = i - 262144; }
    else                 { s = wo; d = wob; off = i - 458752; }
    float4 v = ((const float4*)s)[off];
    bf16x4 o;
    o[0] = (bf16_t)v.x; o[1] = (bf16_t)v.y;
    o[2] = (bf16_t)v.z; o[3] = (bf16_t)v.w;
    ((bf16x4*)d)[off] = o;
}

// ---------------------------------------------------------------------------
// K1 (R9-proven): qkv GEMM, 64x64 tile per one-wave block, grid 32x24.
// ---------------------------------------------------------------------------
__global__ __launch_bounds__(64) void qkv_gemm_kernel(
    const bf16_t* __restrict__ X, const bf16_t* __restrict__ W,
    const float* __restrict__ bias,
    bf16_t* __restrict__ qq, bf16_t* __restrict__ kk, bf16_t* __restrict__ vv)
{
    const int lane = threadIdx.x;
    const int rsel = lane & 15;
    const int koff = (lane >> 4) * 8;
    const int m0 = blockIdx.x * 64;
    const int n0 = blockIdx.y * 64;
    f32x4 acc[4][4] = {};
    const bf16_t* Ap = X + (m0 + rsel) * EMB + koff;
    const bf16_t* Bp = W + (n0 + rsel) * EMB + koff;
#pragma unroll 2
    for (int k0 = 0; k0 < EMB; k0 += 32) {
        bf16x8 af[4], bfr[4];
        for (int i = 0; i < 4; ++i)
            af[i] = *(const bf16x8*)(Ap + i * 16 * EMB + k0);
        for (int j = 0; j < 4; ++j)
            bfr[j] = *(const bf16x8*)(Bp + j * 16 * EMB + k0);
        for (int i = 0; i < 4; ++i)
            for (int j = 0; j < 4; ++j)
                acc[i][j] = __builtin_amdgcn_mfma_f32_16x16x32_bf16(
                    af[i], bfr[j], acc[i][j], 0, 0, 0);
    }
    for (int j = 0; j < 4; ++j) {
        const int n = n0 + j * 16 + rsel;
        const float bn = bias[n];
        const int sec = n >> 9;          // 0=q 1=k 2=v
        const int c = n & 511;
        const int h = c >> 6, e = c & 63;
        for (int i = 0; i < 4; ++i) {
            const int mb = m0 + i * 16 + (lane >> 4) * 4;
            for (int r = 0; r < 4; ++r) {
                int m = mb + r;
                int b = m >> 10, t = m & 1023;
                float val = acc[i][j][r] + bn;
                int di = ((b * NH + h) * T_SEQ + t) * HD + e;
                if (sec == 0) {
                    qq[di] = (bf16_t)fmaxf(val, 0.f);
                } else if (sec == 1) {
                    kk[di] = (bf16_t)fmaxf(val, 0.f);
                } else {
                    vv[di] = (bf16_t)val;
                }
            }
        }
    }
}

// ---------------------------------------------------------------------------
// K2 (merged chunk_sum + chunk_out): per-chunk output with the S/z prefix
// computed in-kernel via MFMA over previous chunks' k,v (fp32 accumulate).
//   PS_c[e][i] = sum_{t<ch*64} cw_t*k'[t][i]*v[t][e]  (A=vT, B=kcT; NT MFMA)
//   then the R9-proven P/nrm/ctx phases.
// LDS reuse: sct/sst/sp serve as kcT/ksT/vT staging during the prefix loop,
// then hold prefix-S (bf16) and the P matrix afterwards.
// ---------------------------------------------------------------------------
__global__ __launch_bounds__(256) void chunk_out_kernel(
    const bf16_t* __restrict__ qq, const bf16_t* __restrict__ kk,
    const bf16_t* __restrict__ vv, bf16_t* __restrict__ Y)
{
    const int blk = blockIdx.x;
    const int bh = blk >> 4, ch = blk & 15;
    __shared__ __align__(16) bf16_t sq [CHUNK * LDA];
    __shared__ __align__(16) bf16_t sk [CHUNK * LDA];
    __shared__ __align__(16) bf16_t svT[CHUNK * LDA];
    __shared__ __align__(16) bf16_t sct[CHUNK * LDA];   // staging kcT -> prefix Sc[e][i]
    __shared__ __align__(16) bf16_t sst[CHUNK * LDA];   // staging ksT -> prefix Ss[e][i]
    __shared__ __align__(16) bf16_t sp [CHUNK * LDA];   // staging vT  -> P matrix
    __shared__ float cwt[CHUNK], swt[CHUNK], cosd[CHUNK];
    __shared__ float zcl[CHUNK], zsl[CHUNK], nrm[CHUNK];

    const int base = blk * CHUNK * HD;
    // ---- stage own chunk: q,k rows; v transposed (R9-proven pattern) ----
    for (int i = threadIdx.x; i < CHUNK * HD / 8; i += 256) {
        int row = i >> 3, g = i & 7;
        ((uint4*)(sq + row * LDA))[g]  = ((const uint4*)(qq + base))[i];
        ((uint4*)(sk + row * LDA))[g]  = ((const uint4*)(kk + base))[i];
        bf16x8 v8 = *(const bf16x8*)(vv + base + i * 8);
        int t = i >> 3, e0 = (i & 7) * 8;
        for (int j = 0; j < 8; ++j) svT[(e0 + j) * LDA + t] = v8[j];
    }
    if (threadIdx.x < CHUNK) {
        int tl = threadIdx.x;
        int tg = ch * CHUNK + tl;
        float angg = 1.5707963267948966f * (float)tg * (1.0f / (float)T_SEQ);
        cwt[tl] = cosf(angg);
        swt[tl] = sinf(angg);
        cosd[tl] = cosf(1.5707963267948966f * (float)tl * (1.0f / (float)T_SEQ));
    }

    const int w = threadIdx.x >> 6;
    const int lane = threadIdx.x & 63;
    const int rsel = lane & 15;
    const int koff = (lane >> 4) * 8;

    // ---- prefix over chunks c < ch: MFMA accumulate in fp32 regs ----
    f32x4 pacC[4] = {};
    f32x4 pacS[4] = {};
    float zacc = 0.f;                 // tid<64: cos-z for i=tid; tid 64..127: sin-z
    for (int c = 0; c < ch; ++c) {
        const int cb = (bh * NCHUNK + c) * CHUNK * HD;
        // stage kcT/ksT (weighted transpose) and vT for chunk c
        for (int i = threadIdx.x; i < CHUNK * HD / 8; i += 256) {
            int t = i >> 3, i0 = (i & 7) * 8;
            float ang = 1.5707963267948966f * (float)(c * CHUNK + t) * (1.0f / (float)T_SEQ);
            float cw = cosf(ang), sw = sinf(ang);
            bf16x8 k8 = *(const bf16x8*)(kk + cb + i * 8);
            bf16x8 v8 = *(const bf16x8*)(vv + cb + i * 8);
            for (int j = 0; j < 8; ++j) {
                float kf = (float)k8[j];
                sct[(i0 + j) * LDA + t] = (bf16_t)(kf * cw);
                sst[(i0 + j) * LDA + t] = (bf16_t)(kf * sw);
                sp [(i0 + j) * LDA + t] = v8[j];
            }
        }
        __syncthreads();
        // PS[e][i] += sum_t vT[e][t] * kT{c,s}[i][t]; wave w owns e rows [16w,16w+16)
        bf16x8 a0 = *(const bf16x8*)(sp + (w * 16 + rsel) * LDA + koff);
        bf16x8 a1 = *(const bf16x8*)(sp + (w * 16 + rsel) * LDA + koff + 32);
        for (int nt = 0; nt < 4; ++nt) {
            const bf16_t* bc = sct + (nt * 16 + rsel) * LDA + koff;
            const bf16_t* bs = sst + (nt * 16 + rsel) * LDA + koff;
            pacC[nt] = __builtin_amdgcn_mfma_f32_16x16x32_bf16(a0, *(const bf16x8*)(bc), pacC[nt], 0, 0, 0);
            pacC[nt] = __builtin_amdgcn_mfma_f32_16x16x32_bf16(a1, *(const bf16x8*)(bc + 32), pacC[nt], 0, 0, 0);
            pacS[nt] = __builtin_amdgcn_mfma_f32_16x16x32_bf16(a0, *(const bf16x8*)(bs), pacS[nt], 0, 0, 0);
            pacS[nt] = __builtin_amdgcn_mfma_f32_16x16x32_bf16(a1, *(const bf16x8*)(bs + 32), pacS[nt], 0, 0, 0);
        }
        // z prefix: row-sums of the weighted kT
        if (threadIdx.x < HD) {
            const bf16x8* pr = (const bf16x8*)(sct + threadIdx.x * LDA);
            for (int g = 0; g < 8; ++g) {
                bf16x8 v8 = pr[g];
                for (int j = 0; j < 8; ++j) zacc += (float)v8[j];
            }
        } else if (threadIdx.x < 2 * HD) {
            const bf16x8* pr = (const bf16x8*)(sst + (threadIdx.x - HD) * LDA);
            for (int g = 0; g < 8; ++g) {
                bf16x8 v8 = pr[g];
                for (int j = 0; j < 8; ++j) zacc += (float)v8[j];
            }
        }
        __syncthreads();   // protect staging buffers before next iteration
    }
    // write prefix into LDS (C layout: col = nt*16+rsel, row = 16w+quad*4+r)
    for (int nt = 0; nt < 4; ++nt) {
        const int i = nt * 16 + rsel;
        const int eb = w * 16 + (lane >> 4) * 4;
        for (int r = 0; r < 4; ++r) {
            sct[(eb + r) * LDA + i] = (bf16_t)pacC[nt][r];
            sst[(eb + r) * LDA + i] = (bf16_t)pacS[nt][r];
        }
    }
    if (threadIdx.x < HD)          zcl[threadIdx.x] = zacc;
    else if (threadIdx.x < 2 * HD) zsl[threadIdx.x - HD] = zacc;
    __syncthreads();

    // ---- P = q' k'^T, scale+mask, bf16 rows (wave-local) [R9 verbatim] ----
    const int myrow = w * 16 + rsel;
    bf16x8 aq0 = *(const bf16x8*)(sq + myrow * LDA + koff);
    bf16x8 aq1 = *(const bf16x8*)(sq + myrow * LDA + koff + 32);
    for (int nt = 0; nt < 4; ++nt) {
        const int n0 = nt * 16;
        f32x4 pacc = {0.f, 0.f, 0.f, 0.f};
        bf16x8 b0 = *(const bf16x8*)(sk + (n0 + rsel) * LDA + koff);
        bf16x8 b1 = *(const bf16x8*)(sk + (n0 + rsel) * LDA + koff + 32);
        pacc = __builtin_amdgcn_mfma_f32_16x16x32_bf16(aq0, b0, pacc, 0, 0, 0);
        pacc = __builtin_amdgcn_mfma_f32_16x16x32_bf16(aq1, b1, pacc, 0, 0, 0);
        const int s = n0 + (lane & 15);
        const int tb = w * 16 + (lane >> 4) * 4;
        for (int r = 0; r < 4; ++r) {
            int t = tb + r;
            float p = (s <= t) ? pacc[r] * cosd[t - s] : 0.f;
            sp[t * LDA + s] = (bf16_t)p;
        }
    }

    // ---- nrm (lanes 0..15 of each wave; rows wave-local) [R9 verbatim] ----
    if (lane < 16) {
        int row = w * 16 + lane;
        float nv = 0.f;
        const bf16x8* pr = (const bf16x8*)(sp + row * LDA);
        for (int g = 0; g < 8; ++g) {
            bf16x8 pv = pr[g];
            for (int j = 0; j < 8; ++j) nv += (float)pv[j];
        }
        float cwr = cwt[row], swr = swt[row];
        const bf16x8* qr = (const bf16x8*)(sq + row * LDA);
        for (int g = 0; g < 8; ++g) {
            bf16x8 qv = qr[g];
            for (int j = 0; j < 8; ++j)
                nv += (float)qv[j] * (cwr * zcl[g * 8 + j] + swr * zsl[g * 8 + j]);
        }
        nrm[row] = nv;
    }

    // ---- ctx = P@V + q'c@Sc + q's@Ss [R9 verbatim] ----
    const float cwq = cwt[myrow], swq = swt[myrow];
    bf16x8 qc0, qc1, qs0, qs1;
    for (int j = 0; j < 8; ++j) {
        qc0[j] = (bf16_t)((float)aq0[j] * cwq);
        qc1[j] = (bf16_t)((float)aq1[j] * cwq);
        qs0[j] = (bf16_t)((float)aq0[j] * swq);
        qs1[j] = (bf16_t)((float)aq1[j] * swq);
    }
    bf16x8 ap0 = *(const bf16x8*)(sp + myrow * LDA + koff);
    bf16x8 ap1 = *(const bf16x8*)(sp + myrow * LDA + koff + 32);

    const int b = bh >> 3, h = bh & 7;
    for (int nt = 0; nt < 4; ++nt) {
        const int n0 = nt * 16;
        const bf16_t* bvp = svT + (n0 + rsel) * LDA + koff;
        const bf16_t* bcp = sct + (n0 + rsel) * LDA + koff;
        const bf16_t* bsp = sst + (n0 + rsel) * LDA + koff;
        f32x4 acc = {0.f, 0.f, 0.f, 0.f};
        acc = __builtin_amdgcn_mfma_f32_16x16x32_bf16(ap0, *(const bf16x8*)(bvp), acc, 0, 0, 0);
        acc = __builtin_amdgcn_mfma_f32_16x16x32_bf16(ap1, *(const bf16x8*)(bvp + 32), acc, 0, 0, 0);
        acc = __builtin_amdgcn_mfma_f32_16x16x32_bf16(qc0, *(const bf16x8*)(bcp), acc, 0, 0, 0);
        acc = __builtin_amdgcn_mfma_f32_16x16x32_bf16(qc1, *(const bf16x8*)(bcp + 32), acc, 0, 0, 0);
        acc = __builtin_amdgcn_mfma_f32_16x16x32_bf16(qs0, *(const bf16x8*)(bsp), acc, 0, 0, 0);
        acc = __builtin_amdgcn_mfma_f32_16x16x32_bf16(qs1, *(const bf16x8*)(bsp + 32), acc, 0, 0, 0);
        const int col = n0 + (lane & 15);
        const int tb = w * 16 + (lane >> 4) * 4;
        for (int r = 0; r < 4; ++r) {
            int row = tb + r;
            float inv = 1.0f / (nrm[row] + 1e-6f);
            int tg = ch * CHUNK + row;
            Y[((b * T_SEQ + tg) * EMB) + h * HD + col] = (bf16_t)(acc[r] * inv);
        }
    }
}

// ---------------------------------------------------------------------------
// K3: out = Y @ w_out^T + b_out, register-blocked 2x2 per wave, fp32 out.
// ---------------------------------------------------------------------------
__global__ __launch_bounds__(256) void out_gemm_kernel(
    const bf16_t* __restrict__ Yb, const bf16_t* __restrict__ W,
    const float* __restrict__ bias, float* __restrict__ out)
{
    const int w = threadIdx.x >> 6;
    const int lane = threadIdx.x & 63;
    const int rsel = lane & 15;
    const int koff = (lane >> 4) * 8;
    const int m0 = blockIdx.x * 64 + (w & 1) * 32;
    const int n0 = blockIdx.y * 64 + (w >> 1) * 32;
    f32x4 acc[2][2] = {};
    const bf16_t* Ap = Yb + (m0 + rsel) * EMB + koff;
    const bf16_t* Bp = W + (n0 + rsel) * EMB + koff;
#pragma unroll 4
    for (int k0 = 0; k0 < EMB; k0 += 32) {
        bf16x8 af[2], bfr[2];
        for (int i = 0; i < 2; ++i)
            af[i] = *(const bf16x8*)(Ap + i * 16 * EMB + k0);
        for (int j = 0; j < 2; ++j)
            bfr[j] = *(const bf16x8*)(Bp + j * 16 * EMB + k0);
        for (int i = 0; i < 2; ++i)
            for (int j = 0; j < 2; ++j)
                acc[i][j] = __builtin_amdgcn_mfma_f32_16x16x32_bf16(
                    af[i], bfr[j], acc[i][j], 0, 0, 0);
    }
    for (int j = 0; j < 2; ++j) {
        const int n = n0 + j * 16 + rsel;
        const float bn = bias[n];
        for (int i = 0; i < 2; ++i) {
            const int mb = m0 + i * 16 + (lane >> 4) * 4;
            for (int r = 0; r < 4; ++r)
                out[(mb + r) * EMB + n] = acc[i][j][r] + bn;
        }
    }
}

extern "C" void kernel_launch(void* const* d_in, const int* in_sizes, int n_in,
                              void* d_out, int out_size, void* d_ws, size_t ws_size,
                              hipStream_t stream) {
    const float* x     = (const float*)d_in[0];
    const float* w_qkv = (const float*)d_in[1];
    const float* b_qkv = (const float*)d_in[2];
    const float* w_out = (const float*)d_in[3];
    const float* b_out = (const float*)d_in[4];
    float* out = (float*)d_out;

    char* w = (char*)d_ws;
    const size_t N_X   = (size_t)BATCH * T_SEQ * EMB;
    const size_t N_WQ  = (size_t)3 * EMB * EMB;
    const size_t N_WO  = (size_t)EMB * EMB;
    bf16_t* xb   = (bf16_t*)w;                 w += N_X  * sizeof(bf16_t);
    bf16_t* wqb  = (bf16_t*)w;                 w += N_WQ * sizeof(bf16_t);
    bf16_t* wob  = (bf16_t*)w;                 w += N_WO * sizeof(bf16_t);
    const size_t SZ_BHTD = (size_t)NBH * T_SEQ * HD * sizeof(bf16_t);
    bf16_t* qq = (bf16_t*)w;                   w += SZ_BHTD;
    bf16_t* kk = (bf16_t*)w;                   w += SZ_BHTD;
    bf16_t* vv = (bf16_t*)w;                   w += SZ_BHTD;
    bf16_t* Y  = (bf16_t*)w;

    cvt3_kernel<<<2048, 256, 0, stream>>>(x, w_qkv, w_out, xb, wqb, wob);
    qkv_gemm_kernel<<<dim3(2048 / 64, 1536 / 64), 64, 0, stream>>>(
        xb, wqb, b_qkv, qq, kk, vv);
    chunk_out_kernel<<<NBLK, 256, 0, stream>>>(qq, kk, vv, Y);
    out_gemm_kernel<<<dim3(2048 / 64, 512 / 64), 256, 0, stream>>>(
        Y, wob, b_out, out);
}

// Round 12
// 123.440 us; speedup vs baseline: 1.9581x; 1.1335x over previous
//
#include <hip/hip_runtime.h>

typedef __bf16 bf16_t;
typedef __bf16 bf16x4 __attribute__((ext_vector_type(4)));
typedef __bf16 bf16x8 __attribute__((ext_vector_type(8)));
typedef float f32x4 __attribute__((ext_vector_type(4)));

#define T_SEQ 1024
#define EMB   512
#define NH    8
#define HD    64
#define BATCH 2
#define NBH   (BATCH*NH)      // 16
#define CHUNK 64
#define NCHUNK (T_SEQ/CHUNK)  // 16
#define NBLK  (NBH*NCHUNK)    // 256
#define LDA   72              // padded LDS row stride

// Identity: with ang_t = (pi/2)*t/T,
//   q_cos[t].k_cos[s] + q_sin[t].k_sin[s] = (q'[t].k'[s]) * cos(ang_t - ang_s)

// ---------------------------------------------------------------------------
// K0: fused fp32 -> bf16 convert for x, w_qkv, w_out (one dispatch).
// ---------------------------------------------------------------------------
__global__ __launch_bounds__(256) void cvt3_kernel(
    const float* __restrict__ x, const float* __restrict__ wq,
    const float* __restrict__ wo,
    bf16_t* __restrict__ xb, bf16_t* __restrict__ wqb, bf16_t* __restrict__ wob)
{
    int i = blockIdx.x * 256 + threadIdx.x;
    const float* s; bf16_t* d; int off;
    if (i < 262144)      { s = x;  d = xb;  off = i; }
    else if (i < 458752) { s = wq; d = wqb; off = i - 262144; }
    else                 { s = wo; d = wob; off = i - 458752; }
    float4 v = ((const float4*)s)[off];
    bf16x4 o;
    o[0] = (bf16_t)v.x; o[1] = (bf16_t)v.y;
    o[2] = (bf16_t)v.z; o[3] = (bf16_t)v.w;
    ((bf16x4*)d)[off] = o;
}

// ---------------------------------------------------------------------------
// K1 (R9-proven + unroll 4): qkv GEMM, 64x64 tile per one-wave block,
// grid 32x24 = 768 blocks (~3 waves/CU everywhere).
// ---------------------------------------------------------------------------
__global__ __launch_bounds__(64) void qkv_gemm_kernel(
    const bf16_t* __restrict__ X, const bf16_t* __restrict__ W,
    const float* __restrict__ bias,
    bf16_t* __restrict__ qq, bf16_t* __restrict__ kk, bf16_t* __restrict__ vv)
{
    const int lane = threadIdx.x;
    const int rsel = lane & 15;
    const int koff = (lane >> 4) * 8;
    const int m0 = blockIdx.x * 64;
    const int n0 = blockIdx.y * 64;
    f32x4 acc[4][4] = {};
    const bf16_t* Ap = X + (m0 + rsel) * EMB + koff;
    const bf16_t* Bp = W + (n0 + rsel) * EMB + koff;
#pragma unroll 4
    for (int k0 = 0; k0 < EMB; k0 += 32) {
        bf16x8 af[4], bfr[4];
        for (int i = 0; i < 4; ++i)
            af[i] = *(const bf16x8*)(Ap + i * 16 * EMB + k0);
        for (int j = 0; j < 4; ++j)
            bfr[j] = *(const bf16x8*)(Bp + j * 16 * EMB + k0);
        for (int i = 0; i < 4; ++i)
            for (int j = 0; j < 4; ++j)
                acc[i][j] = __builtin_amdgcn_mfma_f32_16x16x32_bf16(
                    af[i], bfr[j], acc[i][j], 0, 0, 0);
    }
    for (int j = 0; j < 4; ++j) {
        const int n = n0 + j * 16 + rsel;
        const float bn = bias[n];
        const int sec = n >> 9;          // 0=q 1=k 2=v
        const int c = n & 511;
        const int h = c >> 6, e = c & 63;
        for (int i = 0; i < 4; ++i) {
            const int mb = m0 + i * 16 + (lane >> 4) * 4;
            for (int r = 0; r < 4; ++r) {
                int m = mb + r;
                int b = m >> 10, t = m & 1023;
                float val = acc[i][j][r] + bn;
                int di = ((b * NH + h) * T_SEQ + t) * HD + e;
                if (sec == 0) {
                    qq[di] = (bf16_t)fmaxf(val, 0.f);
                } else if (sec == 1) {
                    kk[di] = (bf16_t)fmaxf(val, 0.f);
                } else {
                    vv[di] = (bf16_t)val;
                }
            }
        }
    }
}

// ---------------------------------------------------------------------------
// K2 (R9-proven VALU): per-chunk weighted sums, S stored TRANSPOSED [e][i]:
//   SscT[blk][e][i] = sum_t cw_t*k'[t][i]*v[t][e]   (bf16)
//   zc[blk][i]      = sum_t cw_t*k'[t][i]           (fp32)
// ---------------------------------------------------------------------------
__global__ __launch_bounds__(256) void chunk_sum_kernel(
    const bf16_t* __restrict__ kk, const bf16_t* __restrict__ vv,
    bf16_t* __restrict__ Ssc, bf16_t* __restrict__ Sss,
    float* __restrict__ zc, float* __restrict__ zs)
{
    const int blk = blockIdx.x;
    const int ch = blk & 15;
    __shared__ __align__(16) bf16_t sk[CHUNK * HD];
    __shared__ __align__(16) bf16_t sv[CHUNK * HD];
    __shared__ float cwt[CHUNK], swt[CHUNK];
    const int base = blk * CHUNK * HD;
    for (int i = threadIdx.x; i < CHUNK * HD / 8; i += 256) {
        ((uint4*)sk)[i] = ((const uint4*)(kk + base))[i];
        ((uint4*)sv)[i] = ((const uint4*)(vv + base))[i];
    }
    if (threadIdx.x < CHUNK) {
        int tg = ch * CHUNK + threadIdx.x;
        float ang = 1.5707963267948966f * (float)tg * (1.0f / (float)T_SEQ);
        cwt[threadIdx.x] = cosf(ang);
        swt[threadIdx.x] = sinf(ang);
    }
    __syncthreads();
    const int i  = threadIdx.x & 63;
    const int jg = (threadIdx.x >> 6) * 16;
    float ac[16], as[16];
    for (int jj = 0; jj < 16; ++jj) { ac[jj] = 0.f; as[jj] = 0.f; }
    for (int t = 0; t < CHUNK; ++t) {
        float kv = (float)sk[t * HD + i];
        float kc_ = kv * cwt[t];
        float ks_ = kv * swt[t];
        for (int jj = 0; jj < 16; ++jj) {
            float vj = (float)sv[t * HD + jg + jj];
            ac[jj] += kc_ * vj;
            as[jj] += ks_ * vj;
        }
    }
    bf16_t* oc = Ssc + blk * HD * HD;
    bf16_t* os = Sss + blk * HD * HD;
    for (int jj = 0; jj < 16; ++jj) {
        oc[(jg + jj) * HD + i] = (bf16_t)ac[jj];   // transposed: [e][i]
        os[(jg + jj) * HD + i] = (bf16_t)as[jj];
    }
    if (threadIdx.x < HD) {
        int ii = threadIdx.x;
        float s = 0.f;
        for (int t = 0; t < CHUNK; ++t) s += (float)sk[t * HD + ii] * cwt[t];
        zc[blk * HD + ii] = s;
    } else if (threadIdx.x < 2 * HD) {
        int ii = threadIdx.x - HD;
        float s = 0.f;
        for (int t = 0; t < CHUNK; ++t) s += (float)sk[t * HD + ii] * swt[t];
        zs[blk * HD + ii] = s;
    }
}

// ---------------------------------------------------------------------------
// K3 (R9 + swizzled svT): per-chunk output with on-the-fly S/z prefix.
// svT uses granule rotation rot(e)=e>>3 so the transpose scatter hits all
// 32 banks (was ~16-way conflicted: with LDA=72, 36==4 mod 32 kills the
// row term). Reads add the same rotation to the B-frag address.
// ---------------------------------------------------------------------------
__global__ __launch_bounds__(256) void chunk_out_kernel(
    const bf16_t* __restrict__ qq, const bf16_t* __restrict__ kk,
    const bf16_t* __restrict__ vv,
    const bf16_t* __restrict__ SscT, const bf16_t* __restrict__ SssT,
    const float* __restrict__ zc, const float* __restrict__ zs,
    bf16_t* __restrict__ Y)
{
    const int blk = blockIdx.x;
    const int bh = blk >> 4, ch = blk & 15;
    __shared__ __align__(16) bf16_t sq [CHUNK * LDA];
    __shared__ __align__(16) bf16_t sk [CHUNK * LDA];
    __shared__ __align__(16) bf16_t svT[CHUNK * LDA];
    __shared__ __align__(16) bf16_t sct[CHUNK * LDA];
    __shared__ __align__(16) bf16_t sst[CHUNK * LDA];
    __shared__ __align__(16) bf16_t sp [CHUNK * LDA];
    __shared__ float cwt[CHUNK], swt[CHUNK], cosd[CHUNK];
    __shared__ float zcl[CHUNK], zsl[CHUNK], nrm[CHUNK];

    const int base = blk * CHUNK * HD;
    for (int i = threadIdx.x; i < CHUNK * HD / 8; i += 256) {
        int row = i >> 3, g = i & 7;
        ((uint4*)(sq + row * LDA))[g]  = ((const uint4*)(qq + base))[i];
        ((uint4*)(sk + row * LDA))[g]  = ((const uint4*)(kk + base))[i];
        // V transpose with granule rotation: elem (t, e=8b+j) stored at
        // row e, physical granule ((t>>3)+b)&7, slot t&7.
        bf16x8 v8 = *(const bf16x8*)(vv + base + i * 8);
        int t = i >> 3, b = i & 7;
        int tg8 = t >> 3, tf = t & 7;
        for (int j = 0; j < 8; ++j) {
            int e = b * 8 + j;
            int pg = (tg8 + b) & 7;
            svT[e * LDA + pg * 8 + tf] = v8[j];
        }
    }
    // on-the-fly exclusive prefix of S over chunks < ch (fp32 acc -> bf16 LDS)
    {
        const int e0 = threadIdx.x * 16;            // flat elems [e0, e0+16)
        float accC[16], accS[16];
        for (int j = 0; j < 16; ++j) { accC[j] = 0.f; accS[j] = 0.f; }
        const int sb = bh * NCHUNK * HD * HD + e0;
        for (int c = 0; c < ch; ++c) {
            const bf16x8* pc = (const bf16x8*)(SscT + sb + c * HD * HD);
            const bf16x8* ps = (const bf16x8*)(SssT + sb + c * HD * HD);
            bf16x8 c0 = pc[0], c1 = pc[1], s0 = ps[0], s1 = ps[1];
            for (int j = 0; j < 8; ++j) {
                accC[j] += (float)c0[j];  accC[8 + j] += (float)c1[j];
                accS[j] += (float)s0[j];  accS[8 + j] += (float)s1[j];
            }
        }
        const int row = threadIdx.x >> 2, col = (threadIdx.x & 3) * 16;
        bf16x8 oc0, oc1, os0, os1;
        for (int j = 0; j < 8; ++j) {
            oc0[j] = (bf16_t)accC[j];  oc1[j] = (bf16_t)accC[8 + j];
            os0[j] = (bf16_t)accS[j];  os1[j] = (bf16_t)accS[8 + j];
        }
        *(bf16x8*)(sct + row * LDA + col) = oc0;
        *(bf16x8*)(sct + row * LDA + col + 8) = oc1;
        *(bf16x8*)(sst + row * LDA + col) = os0;
        *(bf16x8*)(sst + row * LDA + col + 8) = os1;
    }
    // z prefix + angle tables
    if (threadIdx.x < HD) {
        int tl = threadIdx.x;
        float s = 0.f;
        for (int c = 0; c < ch; ++c) s += zc[(bh * NCHUNK + c) * HD + tl];
        zcl[tl] = s;
        int tg = ch * CHUNK + tl;
        float angg = 1.5707963267948966f * (float)tg * (1.0f / (float)T_SEQ);
        cwt[tl] = cosf(angg);
        swt[tl] = sinf(angg);
        cosd[tl] = cosf(1.5707963267948966f * (float)tl * (1.0f / (float)T_SEQ));
    } else if (threadIdx.x < 2 * HD) {
        int i = threadIdx.x - HD;
        float s = 0.f;
        for (int c = 0; c < ch; ++c) s += zs[(bh * NCHUNK + c) * HD + i];
        zsl[i] = s;
    }
    __syncthreads();

    const int w = threadIdx.x >> 6;
    const int lane = threadIdx.x & 63;
    const int rsel = lane & 15;
    const int koff = (lane >> 4) * 8;
    const int myrow = w * 16 + rsel;

    // ---- P = q' k'^T, scale+mask, bf16 rows (wave-local) ----
    bf16x8 aq0 = *(const bf16x8*)(sq + myrow * LDA + koff);
    bf16x8 aq1 = *(const bf16x8*)(sq + myrow * LDA + koff + 32);
    for (int nt = 0; nt < 4; ++nt) {
        const int n0 = nt * 16;
        f32x4 pacc = {0.f, 0.f, 0.f, 0.f};
        bf16x8 b0 = *(const bf16x8*)(sk + (n0 + rsel) * LDA + koff);
        bf16x8 b1 = *(const bf16x8*)(sk + (n0 + rsel) * LDA + koff + 32);
        pacc = __builtin_amdgcn_mfma_f32_16x16x32_bf16(aq0, b0, pacc, 0, 0, 0);
        pacc = __builtin_amdgcn_mfma_f32_16x16x32_bf16(aq1, b1, pacc, 0, 0, 0);
        const int s = n0 + (lane & 15);
        const int tb = w * 16 + (lane >> 4) * 4;
        for (int r = 0; r < 4; ++r) {
            int t = tb + r;
            float p = (s <= t) ? pacc[r] * cosd[t - s] : 0.f;
            sp[t * LDA + s] = (bf16_t)p;
        }
    }

    // ---- nrm (lanes 0..15 of each wave; rows wave-local) ----
    if (lane < 16) {
        int row = w * 16 + lane;
        float nv = 0.f;
        const bf16x8* pr = (const bf16x8*)(sp + row * LDA);
        for (int g = 0; g < 8; ++g) {
            bf16x8 pv = pr[g];
            for (int j = 0; j < 8; ++j) nv += (float)pv[j];
        }
        float cwr = cwt[row], swr = swt[row];
        const bf16x8* qr = (const bf16x8*)(sq + row * LDA);
        for (int g = 0; g < 8; ++g) {
            bf16x8 qv = qr[g];
            for (int j = 0; j < 8; ++j)
                nv += (float)qv[j] * (cwr * zcl[g * 8 + j] + swr * zsl[g * 8 + j]);
        }
        nrm[row] = nv;
    }

    // ---- ctx = P@V + q'c@Sc + q's@Ss ----
    const float cwq = cwt[myrow], swq = swt[myrow];
    bf16x8 qc0, qc1, qs0, qs1;
    for (int j = 0; j < 8; ++j) {
        qc0[j] = (bf16_t)((float)aq0[j] * cwq);
        qc1[j] = (bf16_t)((float)aq1[j] * cwq);
        qs0[j] = (bf16_t)((float)aq0[j] * swq);
        qs1[j] = (bf16_t)((float)aq1[j] * swq);
    }
    bf16x8 ap0 = *(const bf16x8*)(sp + myrow * LDA + koff);
    bf16x8 ap1 = *(const bf16x8*)(sp + myrow * LDA + koff + 32);

    const int b = bh >> 3, h = bh & 7;
    const int g0 = koff >> 3;                       // logical granule 0..3
    for (int nt = 0; nt < 4; ++nt) {
        const int n0 = nt * 16;
        const int ee = n0 + rsel;
        const int rot = (ee >> 3) & 7;
        const bf16_t* bvp0 = svT + ee * LDA + (((g0 + rot) & 7) << 3);
        const bf16_t* bvp1 = svT + ee * LDA + (((g0 + 4 + rot) & 7) << 3);
        const bf16_t* bcp = sct + ee * LDA + koff;
        const bf16_t* bsp = sst + ee * LDA + koff;
        f32x4 acc = {0.f, 0.f, 0.f, 0.f};
        acc = __builtin_amdgcn_mfma_f32_16x16x32_bf16(ap0, *(const bf16x8*)(bvp0), acc, 0, 0, 0);
        acc = __builtin_amdgcn_mfma_f32_16x16x32_bf16(ap1, *(const bf16x8*)(bvp1), acc, 0, 0, 0);
        acc = __builtin_amdgcn_mfma_f32_16x16x32_bf16(qc0, *(const bf16x8*)(bcp), acc, 0, 0, 0);
        acc = __builtin_amdgcn_mfma_f32_16x16x32_bf16(qc1, *(const bf16x8*)(bcp + 32), acc, 0, 0, 0);
        acc = __builtin_amdgcn_mfma_f32_16x16x32_bf16(qs0, *(const bf16x8*)(bsp), acc, 0, 0, 0);
        acc = __builtin_amdgcn_mfma_f32_16x16x32_bf16(qs1, *(const bf16x8*)(bsp + 32), acc, 0, 0, 0);
        const int col = n0 + (lane & 15);
        const int tb = w * 16 + (lane >> 4) * 4;
        for (int r = 0; r < 4; ++r) {
            int row = tb + r;
            float inv = 1.0f / (nrm[row] + 1e-6f);
            int tg = ch * CHUNK + row;
            Y[((b * T_SEQ + tg) * EMB) + h * HD + col] = (bf16_t)(acc[r] * inv);
        }
    }
}

// ---------------------------------------------------------------------------
// K4: out = Y @ w_out^T + b_out, register-blocked 2x2 per wave, fp32 out.
// ---------------------------------------------------------------------------
__global__ __launch_bounds__(256) void out_gemm_kernel(
    const bf16_t* __restrict__ Yb, const bf16_t* __restrict__ W,
    const float* __restrict__ bias, float* __restrict__ out)
{
    const int w = threadIdx.x >> 6;
    const int lane = threadIdx.x & 63;
    const int rsel = lane & 15;
    const int koff = (lane >> 4) * 8;
    const int m0 = blockIdx.x * 64 + (w & 1) * 32;
    const int n0 = blockIdx.y * 64 + (w >> 1) * 32;
    f32x4 acc[2][2] = {};
    const bf16_t* Ap = Yb + (m0 + rsel) * EMB + koff;
    const bf16_t* Bp = W + (n0 + rsel) * EMB + koff;
#pragma unroll 4
    for (int k0 = 0; k0 < EMB; k0 += 32) {
        bf16x8 af[2], bfr[2];
        for (int i = 0; i < 2; ++i)
            af[i] = *(const bf16x8*)(Ap + i * 16 * EMB + k0);
        for (int j = 0; j < 2; ++j)
            bfr[j] = *(const bf16x8*)(Bp + j * 16 * EMB + k0);
        for (int i = 0; i < 2; ++i)
            for (int j = 0; j < 2; ++j)
                acc[i][j] = __builtin_amdgcn_mfma_f32_16x16x32_bf16(
                    af[i], bfr[j], acc[i][j], 0, 0, 0);
    }
    for (int j = 0; j < 2; ++j) {
        const int n = n0 + j * 16 + rsel;
        const float bn = bias[n];
        for (int i = 0; i < 2; ++i) {
            const int mb = m0 + i * 16 + (lane >> 4) * 4;
            for (int r = 0; r < 4; ++r)
                out[(mb + r) * EMB + n] = acc[i][j][r] + bn;
        }
    }
}

extern "C" void kernel_launch(void* const* d_in, const int* in_sizes, int n_in,
                              void* d_out, int out_size, void* d_ws, size_t ws_size,
                              hipStream_t stream) {
    const float* x     = (const float*)d_in[0];
    const float* w_qkv = (const float*)d_in[1];
    const float* b_qkv = (const float*)d_in[2];
    const float* w_out = (const float*)d_in[3];
    const float* b_out = (const float*)d_in[4];
    float* out = (float*)d_out;

    char* w = (char*)d_ws;
    const size_t N_X   = (size_t)BATCH * T_SEQ * EMB;
    const size_t N_WQ  = (size_t)3 * EMB * EMB;
    const size_t N_WO  = (size_t)EMB * EMB;
    bf16_t* xb   = (bf16_t*)w;                 w += N_X  * sizeof(bf16_t);
    bf16_t* wqb  = (bf16_t*)w;                 w += N_WQ * sizeof(bf16_t);
    bf16_t* wob  = (bf16_t*)w;                 w += N_WO * sizeof(bf16_t);
    const size_t SZ_BHTD = (size_t)NBH * T_SEQ * HD * sizeof(bf16_t);
    bf16_t* qq = (bf16_t*)w;                   w += SZ_BHTD;
    bf16_t* kk = (bf16_t*)w;                   w += SZ_BHTD;
    bf16_t* vv = (bf16_t*)w;                   w += SZ_BHTD;
    bf16_t* Y  = (bf16_t*)w;                   w += SZ_BHTD;
    bf16_t* SscT = (bf16_t*)w;                 w += (size_t)NBLK * HD * HD * sizeof(bf16_t);
    bf16_t* SssT = (bf16_t*)w;                 w += (size_t)NBLK * HD * HD * sizeof(bf16_t);
    float* zc = (float*)w;                     w += (size_t)NBLK * HD * sizeof(float);
    float* zs = (float*)w;

    cvt3_kernel<<<2048, 256, 0, stream>>>(x, w_qkv, w_out, xb, wqb, wob);
    qkv_gemm_kernel<<<dim3(2048 / 64, 1536 / 64), 64, 0, stream>>>(
        xb, wqb, b_qkv, qq, kk, vv);
    chunk_sum_kernel<<<NBLK, 256, 0, stream>>>(kk, vv, SscT, SssT, zc, zs);
    chunk_out_kernel<<<NBLK, 256, 0, stream>>>(qq, kk, vv, SscT, SssT, zc, zs, Y);
    out_gemm_kernel<<<dim3(2048 / 64, 512 / 64), 256, 0, stream>>>(
        Y, wob, b_out, out);
}

// Round 13
// 119.462 us; speedup vs baseline: 2.0233x; 1.0333x over previous
//
#include <hip/hip_runtime.h>

typedef __bf16 bf16_t;
typedef __bf16 bf16x4 __attribute__((ext_vector_type(4)));
typedef __bf16 bf16x8 __attribute__((ext_vector_type(8)));
typedef float f32x4 __attribute__((ext_vector_type(4)));

#define T_SEQ 1024
#define EMB   512
#define NH    8
#define HD    64
#define BATCH 2
#define NBH   (BATCH*NH)      // 16
#define CHUNK 64
#define NCHUNK (T_SEQ/CHUNK)  // 16
#define NBLK  (NBH*NCHUNK)    // 256
#define LDA   72              // padded LDS row stride

// Identity: with ang_t = (pi/2)*t/T,
//   q_cos[t].k_cos[s] + q_sin[t].k_sin[s] = (q'[t].k'[s]) * cos(ang_t - ang_s)

// ---------------------------------------------------------------------------
// K0: fused fp32 -> bf16 convert for x, w_qkv, w_out (one dispatch).
// ---------------------------------------------------------------------------
__global__ __launch_bounds__(256) void cvt3_kernel(
    const float* __restrict__ x, const float* __restrict__ wq,
    const float* __restrict__ wo,
    bf16_t* __restrict__ xb, bf16_t* __restrict__ wqb, bf16_t* __restrict__ wob)
{
    int i = blockIdx.x * 256 + threadIdx.x;
    const float* s; bf16_t* d; int off;
    if (i < 262144)      { s = x;  d = xb;  off = i; }
    else if (i < 458752) { s = wq; d = wqb; off = i - 262144; }
    else                 { s = wo; d = wob; off = i - 458752; }
    float4 v = ((const float4*)s)[off];
    bf16x4 o;
    o[0] = (bf16_t)v.x; o[1] = (bf16_t)v.y;
    o[2] = (bf16_t)v.z; o[3] = (bf16_t)v.w;
    ((bf16x4*)d)[off] = o;
}

// ---------------------------------------------------------------------------
// K1: qkv GEMM, 64x64 tile per one-wave block, grid 32x24 = 768 blocks.
// ---------------------------------------------------------------------------
__global__ __launch_bounds__(64) void qkv_gemm_kernel(
    const bf16_t* __restrict__ X, const bf16_t* __restrict__ W,
    const float* __restrict__ bias,
    bf16_t* __restrict__ qq, bf16_t* __restrict__ kk, bf16_t* __restrict__ vv)
{
    const int lane = threadIdx.x;
    const int rsel = lane & 15;
    const int koff = (lane >> 4) * 8;
    const int m0 = blockIdx.x * 64;
    const int n0 = blockIdx.y * 64;
    f32x4 acc[4][4] = {};
    const bf16_t* Ap = X + (m0 + rsel) * EMB + koff;
    const bf16_t* Bp = W + (n0 + rsel) * EMB + koff;
#pragma unroll 4
    for (int k0 = 0; k0 < EMB; k0 += 32) {
        bf16x8 af[4], bfr[4];
        for (int i = 0; i < 4; ++i)
            af[i] = *(const bf16x8*)(Ap + i * 16 * EMB + k0);
        for (int j = 0; j < 4; ++j)
            bfr[j] = *(const bf16x8*)(Bp + j * 16 * EMB + k0);
        for (int i = 0; i < 4; ++i)
            for (int j = 0; j < 4; ++j)
                acc[i][j] = __builtin_amdgcn_mfma_f32_16x16x32_bf16(
                    af[i], bfr[j], acc[i][j], 0, 0, 0);
    }
    for (int j = 0; j < 4; ++j) {
        const int n = n0 + j * 16 + rsel;
        const float bn = bias[n];
        const int sec = n >> 9;          // 0=q 1=k 2=v
        const int c = n & 511;
        const int h = c >> 6, e = c & 63;
        for (int i = 0; i < 4; ++i) {
            const int mb = m0 + i * 16 + (lane >> 4) * 4;
            for (int r = 0; r < 4; ++r) {
                int m = mb + r;
                int b = m >> 10, t = m & 1023;
                float val = acc[i][j][r] + bn;
                int di = ((b * NH + h) * T_SEQ + t) * HD + e;
                if (sec == 0) {
                    qq[di] = (bf16_t)fmaxf(val, 0.f);
                } else if (sec == 1) {
                    kk[di] = (bf16_t)fmaxf(val, 0.f);
                } else {
                    vv[di] = (bf16_t)val;
                }
            }
        }
    }
}

// ---------------------------------------------------------------------------
// K2: per-chunk weighted sums, S stored TRANSPOSED [e][i]. z accumulation
// folded into the main loop (jg==0 threads own z for their i; same products
// in the same order as the old tail loops -> bitwise identical).
// ---------------------------------------------------------------------------
__global__ __launch_bounds__(256) void chunk_sum_kernel(
    const bf16_t* __restrict__ kk, const bf16_t* __restrict__ vv,
    bf16_t* __restrict__ Ssc, bf16_t* __restrict__ Sss,
    float* __restrict__ zc, float* __restrict__ zs)
{
    const int blk = blockIdx.x;
    const int ch = blk & 15;
    __shared__ __align__(16) bf16_t sk[CHUNK * HD];
    __shared__ __align__(16) bf16_t sv[CHUNK * HD];
    __shared__ float cwt[CHUNK], swt[CHUNK];
    const int base = blk * CHUNK * HD;
    for (int i = threadIdx.x; i < CHUNK * HD / 8; i += 256) {
        ((uint4*)sk)[i] = ((const uint4*)(kk + base))[i];
        ((uint4*)sv)[i] = ((const uint4*)(vv + base))[i];
    }
    if (threadIdx.x < CHUNK) {
        int tg = ch * CHUNK + threadIdx.x;
        float ang = 1.5707963267948966f * (float)tg * (1.0f / (float)T_SEQ);
        cwt[threadIdx.x] = cosf(ang);
        swt[threadIdx.x] = sinf(ang);
    }
    __syncthreads();
    const int i  = threadIdx.x & 63;
    const int jg = (threadIdx.x >> 6) * 16;
    float ac[16], as[16];
    for (int jj = 0; jj < 16; ++jj) { ac[jj] = 0.f; as[jj] = 0.f; }
    float zca = 0.f, zsa = 0.f;
    const bool zown = (jg == 0);
    for (int t = 0; t < CHUNK; ++t) {
        float kv = (float)sk[t * HD + i];
        float kc_ = kv * cwt[t];
        float ks_ = kv * swt[t];
        if (zown) { zca += kc_; zsa += ks_; }
        for (int jj = 0; jj < 16; ++jj) {
            float vj = (float)sv[t * HD + jg + jj];
            ac[jj] += kc_ * vj;
            as[jj] += ks_ * vj;
        }
    }
    bf16_t* oc = Ssc + blk * HD * HD;
    bf16_t* os = Sss + blk * HD * HD;
    for (int jj = 0; jj < 16; ++jj) {
        oc[(jg + jj) * HD + i] = (bf16_t)ac[jj];   // transposed: [e][i]
        os[(jg + jj) * HD + i] = (bf16_t)as[jj];
    }
    if (zown) {
        zc[blk * HD + i] = zca;
        zs[blk * HD + i] = zsa;
    }
}

// ---------------------------------------------------------------------------
// K3: per-chunk output with on-the-fly S/z prefix (unroll-2 on prefix loop)
// and the R12 bank-swizzled svT (granule rotation rot(e)=e>>3).
// ---------------------------------------------------------------------------
__global__ __launch_bounds__(256) void chunk_out_kernel(
    const bf16_t* __restrict__ qq, const bf16_t* __restrict__ kk,
    const bf16_t* __restrict__ vv,
    const bf16_t* __restrict__ SscT, const bf16_t* __restrict__ SssT,
    const float* __restrict__ zc, const float* __restrict__ zs,
    bf16_t* __restrict__ Y)
{
    const int blk = blockIdx.x;
    const int bh = blk >> 4, ch = blk & 15;
    __shared__ __align__(16) bf16_t sq [CHUNK * LDA];
    __shared__ __align__(16) bf16_t sk [CHUNK * LDA];
    __shared__ __align__(16) bf16_t svT[CHUNK * LDA];
    __shared__ __align__(16) bf16_t sct[CHUNK * LDA];
    __shared__ __align__(16) bf16_t sst[CHUNK * LDA];
    __shared__ __align__(16) bf16_t sp [CHUNK * LDA];
    __shared__ float cwt[CHUNK], swt[CHUNK], cosd[CHUNK];
    __shared__ float zcl[CHUNK], zsl[CHUNK], nrm[CHUNK];

    const int base = blk * CHUNK * HD;
    for (int i = threadIdx.x; i < CHUNK * HD / 8; i += 256) {
        int row = i >> 3, g = i & 7;
        ((uint4*)(sq + row * LDA))[g]  = ((const uint4*)(qq + base))[i];
        ((uint4*)(sk + row * LDA))[g]  = ((const uint4*)(kk + base))[i];
        // V transpose with granule rotation (conflict-free; see R12)
        bf16x8 v8 = *(const bf16x8*)(vv + base + i * 8);
        int t = i >> 3, b = i & 7;
        int tg8 = t >> 3, tf = t & 7;
        for (int j = 0; j < 8; ++j) {
            int e = b * 8 + j;
            int pg = (tg8 + b) & 7;
            svT[e * LDA + pg * 8 + tf] = v8[j];
        }
    }
    // on-the-fly exclusive prefix of S over chunks < ch (fp32 acc -> bf16 LDS)
    {
        const int e0 = threadIdx.x * 16;            // flat elems [e0, e0+16)
        float accC[16], accS[16];
        for (int j = 0; j < 16; ++j) { accC[j] = 0.f; accS[j] = 0.f; }
        const int sb = bh * NCHUNK * HD * HD + e0;
#pragma unroll 2
        for (int c = 0; c < ch; ++c) {
            const bf16x8* pc = (const bf16x8*)(SscT + sb + c * HD * HD);
            const bf16x8* ps = (const bf16x8*)(SssT + sb + c * HD * HD);
            bf16x8 c0 = pc[0], c1 = pc[1], s0 = ps[0], s1 = ps[1];
            for (int j = 0; j < 8; ++j) {
                accC[j] += (float)c0[j];  accC[8 + j] += (float)c1[j];
                accS[j] += (float)s0[j];  accS[8 + j] += (float)s1[j];
            }
        }
        const int row = threadIdx.x >> 2, col = (threadIdx.x & 3) * 16;
        bf16x8 oc0, oc1, os0, os1;
        for (int j = 0; j < 8; ++j) {
            oc0[j] = (bf16_t)accC[j];  oc1[j] = (bf16_t)accC[8 + j];
            os0[j] = (bf16_t)accS[j];  os1[j] = (bf16_t)accS[8 + j];
        }
        *(bf16x8*)(sct + row * LDA + col) = oc0;
        *(bf16x8*)(sct + row * LDA + col + 8) = oc1;
        *(bf16x8*)(sst + row * LDA + col) = os0;
        *(bf16x8*)(sst + row * LDA + col + 8) = os1;
    }
    // z prefix + angle tables
    if (threadIdx.x < HD) {
        int tl = threadIdx.x;
        float s = 0.f;
        for (int c = 0; c < ch; ++c) s += zc[(bh * NCHUNK + c) * HD + tl];
        zcl[tl] = s;
        int tg = ch * CHUNK + tl;
        float angg = 1.5707963267948966f * (float)tg * (1.0f / (float)T_SEQ);
        cwt[tl] = cosf(angg);
        swt[tl] = sinf(angg);
        cosd[tl] = cosf(1.5707963267948966f * (float)tl * (1.0f / (float)T_SEQ));
    } else if (threadIdx.x < 2 * HD) {
        int i = threadIdx.x - HD;
        float s = 0.f;
        for (int c = 0; c < ch; ++c) s += zs[(bh * NCHUNK + c) * HD + i];
        zsl[i] = s;
    }
    __syncthreads();

    const int w = threadIdx.x >> 6;
    const int lane = threadIdx.x & 63;
    const int rsel = lane & 15;
    const int koff = (lane >> 4) * 8;
    const int myrow = w * 16 + rsel;

    // ---- P = q' k'^T, scale+mask, bf16 rows (wave-local) ----
    bf16x8 aq0 = *(const bf16x8*)(sq + myrow * LDA + koff);
    bf16x8 aq1 = *(const bf16x8*)(sq + myrow * LDA + koff + 32);
    for (int nt = 0; nt < 4; ++nt) {
        const int n0 = nt * 16;
        f32x4 pacc = {0.f, 0.f, 0.f, 0.f};
        bf16x8 b0 = *(const bf16x8*)(sk + (n0 + rsel) * LDA + koff);
        bf16x8 b1 = *(const bf16x8*)(sk + (n0 + rsel) * LDA + koff + 32);
        pacc = __builtin_amdgcn_mfma_f32_16x16x32_bf16(aq0, b0, pacc, 0, 0, 0);
        pacc = __builtin_amdgcn_mfma_f32_16x16x32_bf16(aq1, b1, pacc, 0, 0, 0);
        const int s = n0 + (lane & 15);
        const int tb = w * 16 + (lane >> 4) * 4;
        for (int r = 0; r < 4; ++r) {
            int t = tb + r;
            float p = (s <= t) ? pacc[r] * cosd[t - s] : 0.f;
            sp[t * LDA + s] = (bf16_t)p;
        }
    }

    // ---- nrm (lanes 0..15 of each wave; rows wave-local) ----
    if (lane < 16) {
        int row = w * 16 + lane;
        float nv = 0.f;
        const bf16x8* pr = (const bf16x8*)(sp + row * LDA);
        for (int g = 0; g < 8; ++g) {
            bf16x8 pv = pr[g];
            for (int j = 0; j < 8; ++j) nv += (float)pv[j];
        }
        float cwr = cwt[row], swr = swt[row];
        const bf16x8* qr = (const bf16x8*)(sq + row * LDA);
        for (int g = 0; g < 8; ++g) {
            bf16x8 qv = qr[g];
            for (int j = 0; j < 8; ++j)
                nv += (float)qv[j] * (cwr * zcl[g * 8 + j] + swr * zsl[g * 8 + j]);
        }
        nrm[row] = nv;
    }

    // ---- ctx = P@V + q'c@Sc + q's@Ss ----
    const float cwq = cwt[myrow], swq = swt[myrow];
    bf16x8 qc0, qc1, qs0, qs1;
    for (int j = 0; j < 8; ++j) {
        qc0[j] = (bf16_t)((float)aq0[j] * cwq);
        qc1[j] = (bf16_t)((float)aq1[j] * cwq);
        qs0[j] = (bf16_t)((float)aq0[j] * swq);
        qs1[j] = (bf16_t)((float)aq1[j] * swq);
    }
    bf16x8 ap0 = *(const bf16x8*)(sp + myrow * LDA + koff);
    bf16x8 ap1 = *(const bf16x8*)(sp + myrow * LDA + koff + 32);

    const int b = bh >> 3, h = bh & 7;
    const int g0 = koff >> 3;                       // logical granule 0..3
    for (int nt = 0; nt < 4; ++nt) {
        const int n0 = nt * 16;
        const int ee = n0 + rsel;
        const int rot = (ee >> 3) & 7;
        const bf16_t* bvp0 = svT + ee * LDA + (((g0 + rot) & 7) << 3);
        const bf16_t* bvp1 = svT + ee * LDA + (((g0 + 4 + rot) & 7) << 3);
        const bf16_t* bcp = sct + ee * LDA + koff;
        const bf16_t* bsp = sst + ee * LDA + koff;
        f32x4 acc = {0.f, 0.f, 0.f, 0.f};
        acc = __builtin_amdgcn_mfma_f32_16x16x32_bf16(ap0, *(const bf16x8*)(bvp0), acc, 0, 0, 0);
        acc = __builtin_amdgcn_mfma_f32_16x16x32_bf16(ap1, *(const bf16x8*)(bvp1), acc, 0, 0, 0);
        acc = __builtin_amdgcn_mfma_f32_16x16x32_bf16(qc0, *(const bf16x8*)(bcp), acc, 0, 0, 0);
        acc = __builtin_amdgcn_mfma_f32_16x16x32_bf16(qc1, *(const bf16x8*)(bcp + 32), acc, 0, 0, 0);
        acc = __builtin_amdgcn_mfma_f32_16x16x32_bf16(qs0, *(const bf16x8*)(bsp), acc, 0, 0, 0);
        acc = __builtin_amdgcn_mfma_f32_16x16x32_bf16(qs1, *(const bf16x8*)(bsp + 32), acc, 0, 0, 0);
        const int col = n0 + (lane & 15);
        const int tb = w * 16 + (lane >> 4) * 4;
        for (int r = 0; r < 4; ++r) {
            int row = tb + r;
            float inv = 1.0f / (nrm[row] + 1e-6f);
            int tg = ch * CHUNK + row;
            Y[((b * T_SEQ + tg) * EMB) + h * HD + col] = (bf16_t)(acc[r] * inv);
        }
    }
}

// ---------------------------------------------------------------------------
// K4: out = Y @ w_out^T + b_out, register-blocked 2x2 per wave, fp32 out.
// ---------------------------------------------------------------------------
__global__ __launch_bounds__(256) void out_gemm_kernel(
    const bf16_t* __restrict__ Yb, const bf16_t* __restrict__ W,
    const float* __restrict__ bias, float* __restrict__ out)
{
    const int w = threadIdx.x >> 6;
    const int lane = threadIdx.x & 63;
    const int rsel = lane & 15;
    const int koff = (lane >> 4) * 8;
    const int m0 = blockIdx.x * 64 + (w & 1) * 32;
    const int n0 = blockIdx.y * 64 + (w >> 1) * 32;
    f32x4 acc[2][2] = {};
    const bf16_t* Ap = Yb + (m0 + rsel) * EMB + koff;
    const bf16_t* Bp = W + (n0 + rsel) * EMB + koff;
#pragma unroll 8
    for (int k0 = 0; k0 < EMB; k0 += 32) {
        bf16x8 af[2], bfr[2];
        for (int i = 0; i < 2; ++i)
            af[i] = *(const bf16x8*)(Ap + i * 16 * EMB + k0);
        for (int j = 0; j < 2; ++j)
            bfr[j] = *(const bf16x8*)(Bp + j * 16 * EMB + k0);
        for (int i = 0; i < 2; ++i)
            for (int j = 0; j < 2; ++j)
                acc[i][j] = __builtin_amdgcn_mfma_f32_16x16x32_bf16(
                    af[i], bfr[j], acc[i][j], 0, 0, 0);
    }
    for (int j = 0; j < 2; ++j) {
        const int n = n0 + j * 16 + rsel;
        const float bn = bias[n];
        for (int i = 0; i < 2; ++i) {
            const int mb = m0 + i * 16 + (lane >> 4) * 4;
            for (int r = 0; r < 4; ++r)
                out[(mb + r) * EMB + n] = acc[i][j][r] + bn;
        }
    }
}

extern "C" void kernel_launch(void* const* d_in, const int* in_sizes, int n_in,
                              void* d_out, int out_size, void* d_ws, size_t ws_size,
                              hipStream_t stream) {
    const float* x     = (const float*)d_in[0];
    const float* w_qkv = (const float*)d_in[1];
    const float* b_qkv = (const float*)d_in[2];
    const float* w_out = (const float*)d_in[3];
    const float* b_out = (const float*)d_in[4];
    float* out = (float*)d_out;

    char* w = (char*)d_ws;
    const size_t N_X   = (size_t)BATCH * T_SEQ * EMB;
    const size_t N_WQ  = (size_t)3 * EMB * EMB;
    const size_t N_WO  = (size_t)EMB * EMB;
    bf16_t* xb   = (bf16_t*)w;                 w += N_X  * sizeof(bf16_t);
    bf16_t* wqb  = (bf16_t*)w;                 w += N_WQ * sizeof(bf16_t);
    bf16_t* wob  = (bf16_t*)w;                 w += N_WO * sizeof(bf16_t);
    const size_t SZ_BHTD = (size_t)NBH * T_SEQ * HD * sizeof(bf16_t);
    bf16_t* qq = (bf16_t*)w;                   w += SZ_BHTD;
    bf16_t* kk = (bf16_t*)w;                   w += SZ_BHTD;
    bf16_t* vv = (bf16_t*)w;                   w += SZ_BHTD;
    bf16_t* Y  = (bf16_t*)w;                   w += SZ_BHTD;
    bf16_t* SscT = (bf16_t*)w;                 w += (size_t)NBLK * HD * HD * sizeof(bf16_t);
    bf16_t* SssT = (bf16_t*)w;                 w += (size_t)NBLK * HD * HD * sizeof(bf16_t);
    float* zc = (float*)w;                     w += (size_t)NBLK * HD * sizeof(float);
    float* zs = (float*)w;

    cvt3_kernel<<<2048, 256, 0, stream>>>(x, w_qkv, w_out, xb, wqb, wob);
    qkv_gemm_kernel<<<dim3(2048 / 64, 1536 / 64), 64, 0, stream>>>(
        xb, wqb, b_qkv, qq, kk, vv);
    chunk_sum_kernel<<<NBLK, 256, 0, stream>>>(kk, vv, SscT, SssT, zc, zs);
    chunk_out_kernel<<<NBLK, 256, 0, stream>>>(qq, kk, vv, SscT, SssT, zc, zs, Y);
    out_gemm_kernel<<<dim3(2048 / 64, 512 / 64), 256, 0, stream>>>(
        Y, wob, b_out, out);
}

// Round 14
// 118.045 us; speedup vs baseline: 2.0476x; 1.0120x over previous
//
#include <hip/hip_runtime.h>

typedef __bf16 bf16_t;
typedef __bf16 bf16x4 __attribute__((ext_vector_type(4)));
typedef __bf16 bf16x8 __attribute__((ext_vector_type(8)));
typedef float f32x4 __attribute__((ext_vector_type(4)));

#define T_SEQ 1024
#define EMB   512
#define NH    8
#define HD    64
#define BATCH 2
#define NBH   (BATCH*NH)      // 16
#define CHUNK 64
#define NCHUNK (T_SEQ/CHUNK)  // 16
#define NBLK  (NBH*NCHUNK)    // 256
#define LDA   72              // padded LDS row stride (chunk_out)
#define LDK   68              // padded LDS row stride (qkv_sum handoff)

// Identity: with ang_t = (pi/2)*t/T,
//   q_cos[t].k_cos[s] + q_sin[t].k_sin[s] = (q'[t].k'[s]) * cos(ang_t - ang_s)

// ---------------------------------------------------------------------------
// K0: fused fp32 -> bf16 convert for x, w_qkv, w_out (one dispatch).
// ---------------------------------------------------------------------------
__global__ __launch_bounds__(256) void cvt3_kernel(
    const float* __restrict__ x, const float* __restrict__ wq,
    const float* __restrict__ wo,
    bf16_t* __restrict__ xb, bf16_t* __restrict__ wqb, bf16_t* __restrict__ wob)
{
    int i = blockIdx.x * 256 + threadIdx.x;
    const float* s; bf16_t* d; int off;
    if (i < 262144)      { s = x;  d = xb;  off = i; }
    else if (i < 458752) { s = wq; d = wqb; off = i - 262144; }
    else                 { s = wo; d = wob; off = i - 458752; }
    float4 v = ((const float4*)s)[off];
    bf16x4 o;
    o[0] = (bf16_t)v.x; o[1] = (bf16_t)v.y;
    o[2] = (bf16_t)v.z; o[3] = (bf16_t)v.w;
    ((bf16x4*)d)[off] = o;
}

// ---------------------------------------------------------------------------
// K1 (merged qkv GEMM + chunk_sum): grid (32 m-tiles, 8 heads) = 256 blocks.
// Waves 0/1/2 run the proven 64x64 one-wave GEMM for q/k/v (n0 = w*512+h*64).
// k/v epilogues also land their tiles in LDS (stride 68 -> conflict-free);
// after one barrier, all 4 waves run the proven chunk_sum body from LDS.
// An m-tile is exactly one (b, chunk): m0 64-aligned -> b = m0>>10,
// ch = (m0&1023)>>6, so this block IS chunk-sum block blk=(b*NH+h)*16+ch.
// ---------------------------------------------------------------------------
__global__ __launch_bounds__(256) void qkv_sum_kernel(
    const bf16_t* __restrict__ X, const bf16_t* __restrict__ W,
    const float* __restrict__ bias,
    bf16_t* __restrict__ qq, bf16_t* __restrict__ kk, bf16_t* __restrict__ vv,
    bf16_t* __restrict__ Ssc, bf16_t* __restrict__ Sss,
    float* __restrict__ zc, float* __restrict__ zs)
{
    __shared__ __align__(16) bf16_t sk[CHUNK * LDK];
    __shared__ __align__(16) bf16_t sv[CHUNK * LDK];
    __shared__ float cwt[CHUNK], swt[CHUNK];

    const int m0 = blockIdx.x * 64;
    const int h  = blockIdx.y;
    const int b  = m0 >> 10;
    const int ch = (m0 & 1023) >> 6;
    const int blk = (b * NH + h) * NCHUNK + ch;

    if (threadIdx.x < CHUNK) {
        int tg = ch * CHUNK + threadIdx.x;
        float ang = 1.5707963267948966f * (float)tg * (1.0f / (float)T_SEQ);
        cwt[threadIdx.x] = cosf(ang);
        swt[threadIdx.x] = sinf(ang);
    }

    const int w = threadIdx.x >> 6;
    const int lane = threadIdx.x & 63;
    if (w < 3) {
        const int rsel = lane & 15;
        const int koff = (lane >> 4) * 8;
        const int n0 = w * 512 + h * 64;
        f32x4 acc[4][4] = {};
        const bf16_t* Ap = X + (m0 + rsel) * EMB + koff;
        const bf16_t* Bp = W + (n0 + rsel) * EMB + koff;
#pragma unroll 4
        for (int k0 = 0; k0 < EMB; k0 += 32) {
            bf16x8 af[4], bfr[4];
            for (int i = 0; i < 4; ++i)
                af[i] = *(const bf16x8*)(Ap + i * 16 * EMB + k0);
            for (int j = 0; j < 4; ++j)
                bfr[j] = *(const bf16x8*)(Bp + j * 16 * EMB + k0);
            for (int i = 0; i < 4; ++i)
                for (int j = 0; j < 4; ++j)
                    acc[i][j] = __builtin_amdgcn_mfma_f32_16x16x32_bf16(
                        af[i], bfr[j], acc[i][j], 0, 0, 0);
        }
        for (int j = 0; j < 4; ++j) {
            const int feat = j * 16 + rsel;           // 0..63 within head
            const float bn = bias[n0 + feat];
            for (int i = 0; i < 4; ++i) {
                const int tl0 = i * 16 + (lane >> 4) * 4;   // local t, 4-aligned
                for (int r = 0; r < 4; ++r) {
                    const int tl = tl0 + r;
                    const int t = (m0 & 1023) + tl;
                    float val = acc[i][j][r] + bn;
                    int di = ((b * NH + h) * T_SEQ + t) * HD + feat;
                    if (w == 0) {
                        qq[di] = (bf16_t)fmaxf(val, 0.f);
                    } else if (w == 1) {
                        bf16_t kb = (bf16_t)fmaxf(val, 0.f);
                        kk[di] = kb;
                        sk[tl * LDK + feat] = kb;
                    } else {
                        bf16_t vb = (bf16_t)val;
                        vv[di] = vb;
                        sv[tl * LDK + feat] = vb;
                    }
                }
            }
        }
    }
    __syncthreads();

    // ---- proven chunk_sum body, reading the LDS handoff (stride LDK) ----
    const int i  = threadIdx.x & 63;
    const int jg = (threadIdx.x >> 6) * 16;
    float ac[16], as[16];
    for (int jj = 0; jj < 16; ++jj) { ac[jj] = 0.f; as[jj] = 0.f; }
    float zca = 0.f, zsa = 0.f;
    const bool zown = (jg == 0);
    for (int t = 0; t < CHUNK; ++t) {
        float kv = (float)sk[t * LDK + i];
        float kc_ = kv * cwt[t];
        float ks_ = kv * swt[t];
        if (zown) { zca += kc_; zsa += ks_; }
        for (int jj = 0; jj < 16; ++jj) {
            float vj = (float)sv[t * LDK + jg + jj];
            ac[jj] += kc_ * vj;
            as[jj] += ks_ * vj;
        }
    }
    bf16_t* oc = Ssc + blk * HD * HD;
    bf16_t* os = Sss + blk * HD * HD;
    for (int jj = 0; jj < 16; ++jj) {
        oc[(jg + jj) * HD + i] = (bf16_t)ac[jj];   // transposed: [e][i]
        os[(jg + jj) * HD + i] = (bf16_t)as[jj];
    }
    if (zown) {
        zc[blk * HD + i] = zca;
        zs[blk * HD + i] = zsa;
    }
}

// ---------------------------------------------------------------------------
// K2: per-chunk output with on-the-fly S/z prefix (unroll-2 prefix loop)
// and the R12 bank-swizzled svT (granule rotation rot(e)=e>>3).
// ---------------------------------------------------------------------------
__global__ __launch_bounds__(256) void chunk_out_kernel(
    const bf16_t* __restrict__ qq, const bf16_t* __restrict__ kk,
    const bf16_t* __restrict__ vv,
    const bf16_t* __restrict__ SscT, const bf16_t* __restrict__ SssT,
    const float* __restrict__ zc, const float* __restrict__ zs,
    bf16_t* __restrict__ Y)
{
    const int blk = blockIdx.x;
    const int bh = blk >> 4, ch = blk & 15;
    __shared__ __align__(16) bf16_t sq [CHUNK * LDA];
    __shared__ __align__(16) bf16_t sk [CHUNK * LDA];
    __shared__ __align__(16) bf16_t svT[CHUNK * LDA];
    __shared__ __align__(16) bf16_t sct[CHUNK * LDA];
    __shared__ __align__(16) bf16_t sst[CHUNK * LDA];
    __shared__ __align__(16) bf16_t sp [CHUNK * LDA];
    __shared__ float cwt[CHUNK], swt[CHUNK], cosd[CHUNK];
    __shared__ float zcl[CHUNK], zsl[CHUNK], nrm[CHUNK];

    const int base = blk * CHUNK * HD;
    for (int i = threadIdx.x; i < CHUNK * HD / 8; i += 256) {
        int row = i >> 3, g = i & 7;
        ((uint4*)(sq + row * LDA))[g]  = ((const uint4*)(qq + base))[i];
        ((uint4*)(sk + row * LDA))[g]  = ((const uint4*)(kk + base))[i];
        // V transpose with granule rotation (conflict-free; see R12)
        bf16x8 v8 = *(const bf16x8*)(vv + base + i * 8);
        int t = i >> 3, bb = i & 7;
        int tg8 = t >> 3, tf = t & 7;
        for (int j = 0; j < 8; ++j) {
            int e = bb * 8 + j;
            int pg = (tg8 + bb) & 7;
            svT[e * LDA + pg * 8 + tf] = v8[j];
        }
    }
    // on-the-fly exclusive prefix of S over chunks < ch (fp32 acc -> bf16 LDS)
    {
        const int e0 = threadIdx.x * 16;            // flat elems [e0, e0+16)
        float accC[16], accS[16];
        for (int j = 0; j < 16; ++j) { accC[j] = 0.f; accS[j] = 0.f; }
        const int sb = bh * NCHUNK * HD * HD + e0;
#pragma unroll 2
        for (int c = 0; c < ch; ++c) {
            const bf16x8* pc = (const bf16x8*)(SscT + sb + c * HD * HD);
            const bf16x8* ps = (const bf16x8*)(SssT + sb + c * HD * HD);
            bf16x8 c0 = pc[0], c1 = pc[1], s0 = ps[0], s1 = ps[1];
            for (int j = 0; j < 8; ++j) {
                accC[j] += (float)c0[j];  accC[8 + j] += (float)c1[j];
                accS[j] += (float)s0[j];  accS[8 + j] += (float)s1[j];
            }
        }
        const int row = threadIdx.x >> 2, col = (threadIdx.x & 3) * 16;
        bf16x8 oc0, oc1, os0, os1;
        for (int j = 0; j < 8; ++j) {
            oc0[j] = (bf16_t)accC[j];  oc1[j] = (bf16_t)accC[8 + j];
            os0[j] = (bf16_t)accS[j];  os1[j] = (bf16_t)accS[8 + j];
        }
        *(bf16x8*)(sct + row * LDA + col) = oc0;
        *(bf16x8*)(sct + row * LDA + col + 8) = oc1;
        *(bf16x8*)(sst + row * LDA + col) = os0;
        *(bf16x8*)(sst + row * LDA + col + 8) = os1;
    }
    // z prefix + angle tables
    if (threadIdx.x < HD) {
        int tl = threadIdx.x;
        float s = 0.f;
        for (int c = 0; c < ch; ++c) s += zc[(bh * NCHUNK + c) * HD + tl];
        zcl[tl] = s;
        int tg = ch * CHUNK + tl;
        float angg = 1.5707963267948966f * (float)tg * (1.0f / (float)T_SEQ);
        cwt[tl] = cosf(angg);
        swt[tl] = sinf(angg);
        cosd[tl] = cosf(1.5707963267948966f * (float)tl * (1.0f / (float)T_SEQ));
    } else if (threadIdx.x < 2 * HD) {
        int i = threadIdx.x - HD;
        float s = 0.f;
        for (int c = 0; c < ch; ++c) s += zs[(bh * NCHUNK + c) * HD + i];
        zsl[i] = s;
    }
    __syncthreads();

    const int w = threadIdx.x >> 6;
    const int lane = threadIdx.x & 63;
    const int rsel = lane & 15;
    const int koff = (lane >> 4) * 8;
    const int myrow = w * 16 + rsel;

    // ---- P = q' k'^T, scale+mask, bf16 rows (wave-local) ----
    bf16x8 aq0 = *(const bf16x8*)(sq + myrow * LDA + koff);
    bf16x8 aq1 = *(const bf16x8*)(sq + myrow * LDA + koff + 32);
    for (int nt = 0; nt < 4; ++nt) {
        const int n0 = nt * 16;
        f32x4 pacc = {0.f, 0.f, 0.f, 0.f};
        bf16x8 b0 = *(const bf16x8*)(sk + (n0 + rsel) * LDA + koff);
        bf16x8 b1 = *(const bf16x8*)(sk + (n0 + rsel) * LDA + koff + 32);
        pacc = __builtin_amdgcn_mfma_f32_16x16x32_bf16(aq0, b0, pacc, 0, 0, 0);
        pacc = __builtin_amdgcn_mfma_f32_16x16x32_bf16(aq1, b1, pacc, 0, 0, 0);
        const int s = n0 + (lane & 15);
        const int tb = w * 16 + (lane >> 4) * 4;
        for (int r = 0; r < 4; ++r) {
            int t = tb + r;
            float p = (s <= t) ? pacc[r] * cosd[t - s] : 0.f;
            sp[t * LDA + s] = (bf16_t)p;
        }
    }

    // ---- nrm (lanes 0..15 of each wave; rows wave-local) ----
    if (lane < 16) {
        int row = w * 16 + lane;
        float nv = 0.f;
        const bf16x8* pr = (const bf16x8*)(sp + row * LDA);
        for (int g = 0; g < 8; ++g) {
            bf16x8 pv = pr[g];
            for (int j = 0; j < 8; ++j) nv += (float)pv[j];
        }
        float cwr = cwt[row], swr = swt[row];
        const bf16x8* qr = (const bf16x8*)(sq + row * LDA);
        for (int g = 0; g < 8; ++g) {
            bf16x8 qv = qr[g];
            for (int j = 0; j < 8; ++j)
                nv += (float)qv[j] * (cwr * zcl[g * 8 + j] + swr * zsl[g * 8 + j]);
        }
        nrm[row] = nv;
    }

    // ---- ctx = P@V + q'c@Sc + q's@Ss ----
    const float cwq = cwt[myrow], swq = swt[myrow];
    bf16x8 qc0, qc1, qs0, qs1;
    for (int j = 0; j < 8; ++j) {
        qc0[j] = (bf16_t)((float)aq0[j] * cwq);
        qc1[j] = (bf16_t)((float)aq1[j] * cwq);
        qs0[j] = (bf16_t)((float)aq0[j] * swq);
        qs1[j] = (bf16_t)((float)aq1[j] * swq);
    }
    bf16x8 ap0 = *(const bf16x8*)(sp + myrow * LDA + koff);
    bf16x8 ap1 = *(const bf16x8*)(sp + myrow * LDA + koff + 32);

    const int b = bh >> 3, h = bh & 7;
    const int g0 = koff >> 3;                       // logical granule 0..3
    for (int nt = 0; nt < 4; ++nt) {
        const int n0 = nt * 16;
        const int ee = n0 + rsel;
        const int rot = (ee >> 3) & 7;
        const bf16_t* bvp0 = svT + ee * LDA + (((g0 + rot) & 7) << 3);
        const bf16_t* bvp1 = svT + ee * LDA + (((g0 + 4 + rot) & 7) << 3);
        const bf16_t* bcp = sct + ee * LDA + koff;
        const bf16_t* bsp = sst + ee * LDA + koff;
        f32x4 acc = {0.f, 0.f, 0.f, 0.f};
        acc = __builtin_amdgcn_mfma_f32_16x16x32_bf16(ap0, *(const bf16x8*)(bvp0), acc, 0, 0, 0);
        acc = __builtin_amdgcn_mfma_f32_16x16x32_bf16(ap1, *(const bf16x8*)(bvp1), acc, 0, 0, 0);
        acc = __builtin_amdgcn_mfma_f32_16x16x32_bf16(qc0, *(const bf16x8*)(bcp), acc, 0, 0, 0);
        acc = __builtin_amdgcn_mfma_f32_16x16x32_bf16(qc1, *(const bf16x8*)(bcp + 32), acc, 0, 0, 0);
        acc = __builtin_amdgcn_mfma_f32_16x16x32_bf16(qs0, *(const bf16x8*)(bsp), acc, 0, 0, 0);
        acc = __builtin_amdgcn_mfma_f32_16x16x32_bf16(qs1, *(const bf16x8*)(bsp + 32), acc, 0, 0, 0);
        const int col = n0 + (lane & 15);
        const int tb = w * 16 + (lane >> 4) * 4;
        for (int r = 0; r < 4; ++r) {
            int row = tb + r;
            float inv = 1.0f / (nrm[row] + 1e-6f);
            int tg = ch * CHUNK + row;
            Y[((b * T_SEQ + tg) * EMB) + h * HD + col] = (bf16_t)(acc[r] * inv);
        }
    }
}

// ---------------------------------------------------------------------------
// K3: out = Y @ w_out^T + b_out, register-blocked 2x2 per wave, fp32 out.
// ---------------------------------------------------------------------------
__global__ __launch_bounds__(256) void out_gemm_kernel(
    const bf16_t* __restrict__ Yb, const bf16_t* __restrict__ W,
    const float* __restrict__ bias, float* __restrict__ out)
{
    const int w = threadIdx.x >> 6;
    const int lane = threadIdx.x & 63;
    const int rsel = lane & 15;
    const int koff = (lane >> 4) * 8;
    const int m0 = blockIdx.x * 64 + (w & 1) * 32;
    const int n0 = blockIdx.y * 64 + (w >> 1) * 32;
    f32x4 acc[2][2] = {};
    const bf16_t* Ap = Yb + (m0 + rsel) * EMB + koff;
    const bf16_t* Bp = W + (n0 + rsel) * EMB + koff;
#pragma unroll 8
    for (int k0 = 0; k0 < EMB; k0 += 32) {
        bf16x8 af[2], bfr[2];
        for (int i = 0; i < 2; ++i)
            af[i] = *(const bf16x8*)(Ap + i * 16 * EMB + k0);
        for (int j = 0; j < 2; ++j)
            bfr[j] = *(const bf16x8*)(Bp + j * 16 * EMB + k0);
        for (int i = 0; i < 2; ++i)
            for (int j = 0; j < 2; ++j)
                acc[i][j] = __builtin_amdgcn_mfma_f32_16x16x32_bf16(
                    af[i], bfr[j], acc[i][j], 0, 0, 0);
    }
    for (int j = 0; j < 2; ++j) {
        const int n = n0 + j * 16 + rsel;
        const float bn = bias[n];
        for (int i = 0; i < 2; ++i) {
            const int mb = m0 + i * 16 + (lane >> 4) * 4;
            for (int r = 0; r < 4; ++r)
                out[(mb + r) * EMB + n] = acc[i][j][r] + bn;
        }
    }
}

extern "C" void kernel_launch(void* const* d_in, const int* in_sizes, int n_in,
                              void* d_out, int out_size, void* d_ws, size_t ws_size,
                              hipStream_t stream) {
    const float* x     = (const float*)d_in[0];
    const float* w_qkv = (const float*)d_in[1];
    const float* b_qkv = (const float*)d_in[2];
    const float* w_out = (const float*)d_in[3];
    const float* b_out = (const float*)d_in[4];
    float* out = (float*)d_out;

    char* w = (char*)d_ws;
    const size_t N_X   = (size_t)BATCH * T_SEQ * EMB;
    const size_t N_WQ  = (size_t)3 * EMB * EMB;
    const size_t N_WO  = (size_t)EMB * EMB;
    bf16_t* xb   = (bf16_t*)w;                 w += N_X  * sizeof(bf16_t);
    bf16_t* wqb  = (bf16_t*)w;                 w += N_WQ * sizeof(bf16_t);
    bf16_t* wob  = (bf16_t*)w;                 w += N_WO * sizeof(bf16_t);
    const size_t SZ_BHTD = (size_t)NBH * T_SEQ * HD * sizeof(bf16_t);
    bf16_t* qq = (bf16_t*)w;                   w += SZ_BHTD;
    bf16_t* kk = (bf16_t*)w;                   w += SZ_BHTD;
    bf16_t* vv = (bf16_t*)w;                   w += SZ_BHTD;
    bf16_t* Y  = (bf16_t*)w;                   w += SZ_BHTD;
    bf16_t* SscT = (bf16_t*)w;                 w += (size_t)NBLK * HD * HD * sizeof(bf16_t);
    bf16_t* SssT = (bf16_t*)w;                 w += (size_t)NBLK * HD * HD * sizeof(bf16_t);
    float* zc = (float*)w;                     w += (size_t)NBLK * HD * sizeof(float);
    float* zs = (float*)w;

    cvt3_kernel<<<2048, 256, 0, stream>>>(x, w_qkv, w_out, xb, wqb, wob);
    qkv_sum_kernel<<<dim3(32, 8), 256, 0, stream>>>(
        xb, wqb, b_qkv, qq, kk, vv, SscT, SssT, zc, zs);
    chunk_out_kernel<<<NBLK, 256, 0, stream>>>(qq, kk, vv, SscT, SssT, zc, zs, Y);
    out_gemm_kernel<<<dim3(2048 / 64, 512 / 64), 256, 0, stream>>>(
        Y, wob, b_out, out);
}